// Round 1
// baseline (1272.364 us; speedup 1.0000x reference)
//
#include <hip/hip_runtime.h>

#define NN 10000
#define D 128
#define NH 4
#define HD 512   // NH * D
#define ZD 64

__device__ __forceinline__ float lrelu(float x){ return x > 0.0f ? x : 0.2f*x; }

__global__ __launch_bounds__(256) void k_deg_init(float* __restrict__ deg){
  int i = blockIdx.x*256 + threadIdx.x;
  if (i < NN) deg[i] = 1.0f;   // self loop
}

__global__ __launch_bounds__(256) void k_deg_count(const int* __restrict__ dst,
                                                   float* __restrict__ deg, int E){
  int i = blockIdx.x*256 + threadIdx.x;
  if (i < E) atomicAdd(&deg[dst[i]], 1.0f);
}

__global__ __launch_bounds__(256) void k_dinv(float* __restrict__ deg){
  int i = blockIdx.x*256 + threadIdx.x;
  if (i < NN) deg[i] = 1.0f / sqrtf(deg[i]);
}

// C[nrows x M] = A[nrows x 128] @ W[128 x M] (+bias, optional relu). M multiple of 64.
__global__ __launch_bounds__(256) void k_gemm(const float* __restrict__ A,
                                              const float* __restrict__ W, int ldw,
                                              const float* __restrict__ bias,
                                              float* __restrict__ C, int ldc,
                                              int nrows, int do_relu){
  __shared__ float As[64][132];   // row-major A tile, padded
  __shared__ float Ws[128][68];   // W tile, padded
  const int tid  = threadIdx.x;
  const int row0 = blockIdx.x*64;
  const int col0 = blockIdx.y*64;
#pragma unroll
  for (int i=0;i<8;i++){
    int f  = tid + i*256;
    int r  = f >> 5;              // 32 float4 per row
    int k4 = (f & 31) << 2;
    int rr = row0 + r;
    float4 v = make_float4(0.f,0.f,0.f,0.f);
    if (rr < nrows) v = *(const float4*)&A[rr*D + k4];
    *(float4*)&As[r][k4] = v;
  }
#pragma unroll
  for (int i=0;i<8;i++){
    int f  = tid + i*256;
    int k  = f >> 4;              // 16 float4 per W row slice
    int c4 = (f & 15) << 2;
    float4 v = *(const float4*)&W[k*ldw + col0 + c4];
    *(float4*)&Ws[k][c4] = v;
  }
  __syncthreads();
  const int tx = tid & 15, ty = tid >> 4;
  float acc[4][4] = {{0.f}};
#pragma unroll 4
  for (int k=0;k<128;k++){
    float4 w = *(const float4*)&Ws[k][tx<<2];
    float wv[4] = {w.x, w.y, w.z, w.w};
    float av[4];
#pragma unroll
    for (int i=0;i<4;i++) av[i] = As[(ty<<2)+i][k];
#pragma unroll
    for (int i=0;i<4;i++)
#pragma unroll
      for (int j=0;j<4;j++) acc[i][j] = fmaf(av[i], wv[j], acc[i][j]);
  }
#pragma unroll
  for (int i=0;i<4;i++){
    int r = row0 + (ty<<2) + i;
    if (r >= nrows) continue;
#pragma unroll
    for (int j=0;j<4;j++){
      int c = col0 + (tx<<2) + j;
      float v = acc[i][j];
      if (bias) v += bias[c];
      if (do_relu) v = fmaxf(v, 0.f);
      C[r*ldc + c] = v;
    }
  }
}

// acc[n][c] = xw[n][c] * dinv[n]^2   (self-loop init)
__global__ __launch_bounds__(256) void k_gcn_self(const float* __restrict__ xw,
                                                  const float* __restrict__ dinv,
                                                  float* __restrict__ acc){
  int t = blockIdx.x*256 + threadIdx.x;
  if (t >= NN*D) return;
  int n = t >> 7;
  float di = dinv[n];
  acc[t] = xw[t] * di * di;
}

__global__ __launch_bounds__(256) void k_gcn_scatter(const float* __restrict__ xw,
                                                     const float* __restrict__ dinv,
                                                     const int* __restrict__ src,
                                                     const int* __restrict__ dst,
                                                     float* __restrict__ acc, int E){
  int t = blockIdx.x*256 + threadIdx.x;
  int e = t >> 5;
  if (e >= E) return;
  int c = (t & 31) << 2;
  int s = src[e], d = dst[e];
  float nm = dinv[s]*dinv[d];
  float4 v = *(const float4*)&xw[s*D + c];
  float* a = &acc[d*D + c];
  atomicAdd(a+0, v.x*nm);
  atomicAdd(a+1, v.y*nm);
  atomicAdd(a+2, v.z*nm);
  atomicAdd(a+3, v.w*nm);
}

__global__ __launch_bounds__(256) void k_bias_relu(float* __restrict__ h,
                                                   const float* __restrict__ b){
  int t = blockIdx.x*256 + threadIdx.x;
  if (t >= NN*D) return;
  h[t] = fmaxf(h[t] + b[t & 127], 0.f);
}

// a_src[n,h], a_dst[n,h]: one wave per (n,h)
__global__ __launch_bounds__(256) void k_att(const float* __restrict__ hg,
                                             const float* __restrict__ att_src,
                                             const float* __restrict__ att_dst,
                                             float* __restrict__ a_src,
                                             float* __restrict__ a_dst){
  int wi   = blockIdx.x*4 + (threadIdx.x >> 6);
  int lane = threadIdx.x & 63;
  if (wi >= NN*NH) return;
  int n = wi >> 2, h = wi & 3;
  const float* row = &hg[n*HD + h*D];
  const float* as  = &att_src[h*D];
  const float* ad  = &att_dst[h*D];
  float v0 = row[lane], v1 = row[lane+64];
  float s = v0*as[lane] + v1*as[lane+64];
  float d = v0*ad[lane] + v1*ad[lane+64];
#pragma unroll
  for (int off=32; off>0; off>>=1){
    s += __shfl_down(s, off);
    d += __shfl_down(d, off);
  }
  if (lane == 0){ a_src[wi] = s; a_dst[wi] = d; }
}

// denom[n,h] = exp(lrelu(a_src[n,h]+a_dst[n,h]))  (self-loop term)
__global__ __launch_bounds__(256) void k_denom_init(const float* __restrict__ a_src,
                                                    const float* __restrict__ a_dst,
                                                    float* __restrict__ denom){
  int t = blockIdx.x*256 + threadIdx.x;
  if (t >= NN*NH) return;
  denom[t] = expf(lrelu(a_src[t] + a_dst[t]));
}

__global__ __launch_bounds__(256) void k_edge_exp(const float* __restrict__ a_src,
                                                  const float* __restrict__ a_dst,
                                                  const int* __restrict__ src,
                                                  const int* __restrict__ dst,
                                                  float* __restrict__ p,
                                                  float* __restrict__ denom, int E){
  int t = blockIdx.x*256 + threadIdx.x;
  int e = t >> 2;
  if (e >= E) return;
  int h = t & 3;
  float x  = lrelu(a_src[src[e]*NH + h] + a_dst[dst[e]*NH + h]);
  float ex = expf(x);
  p[t] = ex;
  atomicAdd(&denom[dst[e]*NH + h], ex);
}

__global__ __launch_bounds__(256) void k_alpha(const int* __restrict__ dst,
                                               const float* __restrict__ denom,
                                               float* __restrict__ p, int E){
  int t = blockIdx.x*256 + threadIdx.x;
  int e = t >> 2;
  if (e >= E) return;
  int h = t & 3;
  p[t] = p[t] / denom[dst[e]*NH + h] * 0.25f;   // fold the head-mean 1/4
}

// acc[n][c] = sum_h alpha_self[n,h] * hg[n,h,c] * 0.25
__global__ __launch_bounds__(256) void k_gat_self(const float* __restrict__ hg,
                                                  const float* __restrict__ a_src,
                                                  const float* __restrict__ a_dst,
                                                  const float* __restrict__ denom,
                                                  float* __restrict__ acc){
  int t = blockIdx.x*256 + threadIdx.x;
  if (t >= NN*D) return;
  int n = t >> 7, c = t & 127;
  float o = 0.f;
#pragma unroll
  for (int h=0; h<NH; h++){
    float w = expf(lrelu(a_src[n*NH+h] + a_dst[n*NH+h])) / denom[n*NH+h] * 0.25f;
    o = fmaf(w, hg[n*HD + h*D + c], o);
  }
  acc[t] = o;
}

__global__ __launch_bounds__(256) void k_gat_scatter(const float* __restrict__ hg,
                                                     const float* __restrict__ p,
                                                     const int* __restrict__ src,
                                                     const int* __restrict__ dst,
                                                     float* __restrict__ acc, int E){
  int t = blockIdx.x*256 + threadIdx.x;
  int e = t >> 5;
  if (e >= E) return;
  int c = (t & 31) << 2;
  int s = src[e], d = dst[e];
  float4 pv = *(const float4*)&p[e*4];
  const float* hb = &hg[s*HD];
  float4 v0 = *(const float4*)&hb[0*D + c];
  float4 v1 = *(const float4*)&hb[1*D + c];
  float4 v2 = *(const float4*)&hb[2*D + c];
  float4 v3 = *(const float4*)&hb[3*D + c];
  float rx = pv.x*v0.x + pv.y*v1.x + pv.z*v2.x + pv.w*v3.x;
  float ry = pv.x*v0.y + pv.y*v1.y + pv.z*v2.y + pv.w*v3.y;
  float rz = pv.x*v0.z + pv.y*v1.z + pv.z*v2.z + pv.w*v3.z;
  float rw = pv.x*v0.w + pv.y*v1.w + pv.z*v2.w + pv.w*v3.w;
  float* a = &acc[d*D + c];
  atomicAdd(a+0, rx);
  atomicAdd(a+1, ry);
  atomicAdd(a+2, rz);
  atomicAdd(a+3, rw);
}

extern "C" void kernel_launch(void* const* d_in, const int* in_sizes, int n_in,
                              void* d_out, int out_size, void* d_ws, size_t ws_size,
                              hipStream_t stream){
  const float* x     = (const float*)d_in[0];
  const int*   ei    = (const int*)d_in[1];
  const float* gcn_w = (const float*)d_in[2];
  const float* gcn_b = (const float*)d_in[3];
  const float* gat_w = (const float*)d_in[4];
  const float* att_s = (const float*)d_in[5];
  const float* att_d = (const float*)d_in[6];
  const float* gat_b = (const float*)d_in[7];
  const float* w1    = (const float*)d_in[8];
  const float* b1    = (const float*)d_in[9];
  const float* w2    = (const float*)d_in[10];
  const float* b2    = (const float*)d_in[11];
  const float* mu_w  = (const float*)d_in[12];
  const float* mu_b  = (const float*)d_in[13];
  const float* lv_w  = (const float*)d_in[14];
  const float* lv_b  = (const float*)d_in[15];
  const int E = in_sizes[1] / 2;
  const int* src = ei;
  const int* dst = ei + E;

  float* ws    = (float*)d_ws;
  float* xw    = ws;                 // N*128  (later reused as h3)
  float* h1    = xw + NN*D;          // N*128  (GCN acc -> h1; later h4)
  float* h2    = h1 + NN*D;          // N*128  (GAT acc -> h2)
  float* hg    = h2 + NN*D;          // N*512
  float* dinv  = hg + NN*HD;         // N
  float* a_src = dinv + NN;          // N*4
  float* a_dst = a_src + NN*NH;      // N*4
  float* denom = a_dst + NN*NH;      // N*4
  float* p     = denom + NN*NH;      // E*4

  const int gN   = (NN + 255)/256;
  const int gND  = (NN*D + 255)/256;
  const int gE   = (E + 255)/256;
  const int gE4  = (E*4 + 255)/256;
  const int gE32 = (E*32 + 255)/256;
  const int gNH  = (NN*NH + 255)/256;
  const int gR   = (NN + 63)/64;

  // degree / norm
  k_deg_init<<<gN, 256, 0, stream>>>(dinv);
  k_deg_count<<<gE, 256, 0, stream>>>(dst, dinv, E);
  k_dinv<<<gN, 256, 0, stream>>>(dinv);

  // GCN
  k_gemm<<<dim3(gR,2), 256, 0, stream>>>(x, gcn_w, D, nullptr, xw, D, NN, 0);
  k_gcn_self<<<gND, 256, 0, stream>>>(xw, dinv, h1);
  k_gcn_scatter<<<gE32, 256, 0, stream>>>(xw, dinv, src, dst, h1, E);
  k_bias_relu<<<gND, 256, 0, stream>>>(h1, gcn_b);

  // GAT
  k_gemm<<<dim3(gR,8), 256, 0, stream>>>(h1, gat_w, HD, nullptr, hg, HD, NN, 0);
  k_att<<<(NN*NH + 3)/4, 256, 0, stream>>>(hg, att_s, att_d, a_src, a_dst);
  k_denom_init<<<gNH, 256, 0, stream>>>(a_src, a_dst, denom);
  k_edge_exp<<<gE4, 256, 0, stream>>>(a_src, a_dst, src, dst, p, denom, E);
  k_alpha<<<gE4, 256, 0, stream>>>(dst, denom, p, E);
  k_gat_self<<<gND, 256, 0, stream>>>(hg, a_src, a_dst, denom, h2);
  k_gat_scatter<<<gE32, 256, 0, stream>>>(hg, p, src, dst, h2, E);
  k_bias_relu<<<gND, 256, 0, stream>>>(h2, gat_b);

  // MLP + heads
  k_gemm<<<dim3(gR,2), 256, 0, stream>>>(h2, w1, D, b1, xw, D, NN, 1);   // h3 = xw buf
  k_gemm<<<dim3(gR,2), 256, 0, stream>>>(xw, w2, D, b2, h1, D, NN, 1);   // h4 = h1 buf
  float* out = (float*)d_out;
  k_gemm<<<dim3(gR,1), 256, 0, stream>>>(h1, mu_w, ZD, mu_b, out, ZD, NN, 0);
  k_gemm<<<dim3(gR,1), 256, 0, stream>>>(h1, lv_w, ZD, lv_b, out + NN*ZD, ZD, NN, 0);
}

// Round 2
// 283.640 us; speedup vs baseline: 4.4858x; 4.4858x over previous
//
#include <hip/hip_runtime.h>

#define NN 10000
#define D 128
#define NH 4
#define HD 512   // NH * D
#define ZD 64

__device__ __forceinline__ float lrelu(float x){ return x > 0.0f ? x : 0.2f*x; }

// ---------------- CSR build ----------------
__global__ __launch_bounds__(256) void k_zero_int(int* __restrict__ a, int n){
  int i = blockIdx.x*256 + threadIdx.x;
  if (i < n) a[i] = 0;
}

__global__ __launch_bounds__(256) void k_hist(const int* __restrict__ dst,
                                              int* __restrict__ deg, int E){
  int i = blockIdx.x*256 + threadIdx.x;
  if (i < E) atomicAdd(&deg[dst[i]], 1);
}

// single block of 1024: exclusive scan of deg[0..NN) -> ioff; reset cursor(=deg buf) to ioff
__global__ __launch_bounds__(1024) void k_scan(int* __restrict__ deg,
                                               int* __restrict__ ioff){
  __shared__ int part[1024];
  const int tid = threadIdx.x;
  const int base = tid*10;
  int local[10]; int s = 0;
#pragma unroll
  for (int i=0;i<10;i++){
    int idx = base+i;
    int v = (idx < NN) ? deg[idx] : 0;
    local[i] = s; s += v;
  }
  part[tid] = s;
  __syncthreads();
  for (int o=1;o<1024;o<<=1){
    int v = (tid>=o) ? part[tid-o] : 0;
    __syncthreads();
    part[tid] += v;
    __syncthreads();
  }
  int excl = part[tid] - s;
#pragma unroll
  for (int i=0;i<10;i++){
    int idx = base+i;
    if (idx < NN){
      int o = excl + local[i];
      ioff[idx] = o;
      deg[idx]  = o;    // cursor reset
    }
  }
  if (tid == 1023) ioff[NN] = part[1023];
}

__global__ __launch_bounds__(256) void k_dinv(const int* __restrict__ ioff,
                                              float* __restrict__ dinv){
  int i = blockIdx.x*256 + threadIdx.x;
  if (i < NN) dinv[i] = rsqrtf(1.0f + (float)(ioff[i+1]-ioff[i]));
}

__global__ __launch_bounds__(256) void k_fill(const int* __restrict__ src,
                                              const int* __restrict__ dst,
                                              int* __restrict__ cur,
                                              int* __restrict__ csr, int E){
  int i = blockIdx.x*256 + threadIdx.x;
  if (i >= E) return;
  int pos = atomicAdd(&cur[dst[i]], 1);
  csr[pos] = src[i];
}

// ---------------- GEMM ----------------
// C[nrows x M] = A[nrows x 128] @ W[128 x M] (+bias, optional relu). M multiple of 64.
__global__ __launch_bounds__(256) void k_gemm(const float* __restrict__ A,
                                              const float* __restrict__ W, int ldw,
                                              const float* __restrict__ bias,
                                              float* __restrict__ C, int ldc,
                                              int nrows, int do_relu){
  __shared__ float As[64][132];
  __shared__ float Ws[128][68];
  const int tid  = threadIdx.x;
  const int row0 = blockIdx.x*64;
  const int col0 = blockIdx.y*64;
#pragma unroll
  for (int i=0;i<8;i++){
    int f  = tid + i*256;
    int r  = f >> 5;
    int k4 = (f & 31) << 2;
    int rr = row0 + r;
    float4 v = make_float4(0.f,0.f,0.f,0.f);
    if (rr < nrows) v = *(const float4*)&A[rr*D + k4];
    *(float4*)&As[r][k4] = v;
  }
#pragma unroll
  for (int i=0;i<8;i++){
    int f  = tid + i*256;
    int k  = f >> 4;
    int c4 = (f & 15) << 2;
    float4 v = *(const float4*)&W[k*ldw + col0 + c4];
    *(float4*)&Ws[k][c4] = v;
  }
  __syncthreads();
  const int tx = tid & 15, ty = tid >> 4;
  float acc[4][4] = {{0.f}};
#pragma unroll 4
  for (int k=0;k<128;k++){
    float4 w = *(const float4*)&Ws[k][tx<<2];
    float wv[4] = {w.x, w.y, w.z, w.w};
    float av[4];
#pragma unroll
    for (int i=0;i<4;i++) av[i] = As[(ty<<2)+i][k];
#pragma unroll
    for (int i=0;i<4;i++)
#pragma unroll
      for (int j=0;j<4;j++) acc[i][j] = fmaf(av[i], wv[j], acc[i][j]);
  }
#pragma unroll
  for (int i=0;i<4;i++){
    int r = row0 + (ty<<2) + i;
    if (r >= nrows) continue;
#pragma unroll
    for (int j=0;j<4;j++){
      int c = col0 + (tx<<2) + j;
      float v = acc[i][j];
      if (bias) v += bias[c];
      if (do_relu) v = fmaxf(v, 0.f);
      C[r*ldc + c] = v;
    }
  }
}

// ---------------- GCN gather: one wave per node ----------------
// out[n][c] = relu( dinv[n] * ( dinv[n]*xw[n][c] + sum_e dinv[s]*xw[s][c] ) + b[c] )
__global__ __launch_bounds__(256) void k_gcn_agg(const float* __restrict__ xw,
                                                 const float* __restrict__ dinv,
                                                 const int* __restrict__ ioff,
                                                 const int* __restrict__ csr,
                                                 const float* __restrict__ bias,
                                                 float* __restrict__ out){
  int w = blockIdx.x*4 + (threadIdx.x >> 6);
  if (w >= NN) return;
  int lane = threadIdx.x & 63;
  int c = lane << 1;
  int beg = ioff[w], end = ioff[w+1];
  float din = dinv[w];
  float2 sv = *(const float2*)&xw[w*D + c];
  float ax = sv.x*din, ay = sv.y*din;
  int j = beg;
  for (; j+1 < end; j += 2){
    int s0 = csr[j], s1 = csr[j+1];
    float d0 = dinv[s0], d1 = dinv[s1];
    float2 v0 = *(const float2*)&xw[s0*D + c];
    float2 v1 = *(const float2*)&xw[s1*D + c];
    ax += d0*v0.x + d1*v1.x;
    ay += d0*v0.y + d1*v1.y;
  }
  if (j < end){
    int s0 = csr[j];
    float d0 = dinv[s0];
    float2 v0 = *(const float2*)&xw[s0*D + c];
    ax += d0*v0.x;
    ay += d0*v0.y;
  }
  out[w*D + c]     = fmaxf(fmaf(ax, din, bias[c]),   0.f);
  out[w*D + c + 1] = fmaxf(fmaf(ay, din, bias[c+1]), 0.f);
}

// ---------------- GAT attention coefficients ----------------
__global__ __launch_bounds__(256) void k_att(const float* __restrict__ hg,
                                             const float* __restrict__ att_src,
                                             const float* __restrict__ att_dst,
                                             float* __restrict__ a_src,
                                             float* __restrict__ a_dst){
  int wi   = blockIdx.x*4 + (threadIdx.x >> 6);
  int lane = threadIdx.x & 63;
  if (wi >= NN*NH) return;
  int n = wi >> 2, h = wi & 3;
  const float* row = &hg[n*HD + h*D];
  const float* as  = &att_src[h*D];
  const float* ad  = &att_dst[h*D];
  float v0 = row[lane], v1 = row[lane+64];
  float s = v0*as[lane] + v1*as[lane+64];
  float d = v0*ad[lane] + v1*ad[lane+64];
#pragma unroll
  for (int off=32; off>0; off>>=1){
    s += __shfl_down(s, off);
    d += __shfl_down(d, off);
  }
  if (lane == 0){ a_src[wi] = s; a_dst[wi] = d; }
}

// ---------------- GAT gather: one wave per node ----------------
__global__ __launch_bounds__(256) void k_gat_agg(const float* __restrict__ hg,
                                                 const float* __restrict__ a_src,
                                                 const float* __restrict__ a_dst,
                                                 const int* __restrict__ ioff,
                                                 const int* __restrict__ csr,
                                                 const float* __restrict__ bias,
                                                 float* __restrict__ out){
  int w = blockIdx.x*4 + (threadIdx.x >> 6);
  if (w >= NN) return;
  int lane = threadIdx.x & 63;
  int c = lane << 1;
  int beg = ioff[w], end = ioff[w+1];
  float4 ad = *(const float4*)&a_dst[w*4];

  // ---- pass 1: softmax denominators (lane-parallel over edges) ----
  float d0=0.f, d1=0.f, d2=0.f, d3=0.f;
  for (int j = beg + lane; j < end; j += 64){
    int s = csr[j];
    float4 as = *(const float4*)&a_src[s*4];
    d0 += __expf(lrelu(as.x + ad.x));
    d1 += __expf(lrelu(as.y + ad.y));
    d2 += __expf(lrelu(as.z + ad.z));
    d3 += __expf(lrelu(as.w + ad.w));
  }
#pragma unroll
  for (int o=32; o>0; o>>=1){
    d0 += __shfl_xor(d0, o);
    d1 += __shfl_xor(d1, o);
    d2 += __shfl_xor(d2, o);
    d3 += __shfl_xor(d3, o);
  }
  float4 asn = *(const float4*)&a_src[w*4];
  float e0 = __expf(lrelu(asn.x + ad.x));
  float e1 = __expf(lrelu(asn.y + ad.y));
  float e2 = __expf(lrelu(asn.z + ad.z));
  float e3 = __expf(lrelu(asn.w + ad.w));
  d0 += e0; d1 += e1; d2 += e2; d3 += e3;
  float w0 = 0.25f/d0, w1 = 0.25f/d1, w2 = 0.25f/d2, w3 = 0.25f/d3;

  // ---- pass 2: weighted feature gather ----
  const float* hn = &hg[w*HD];
  float a0 = e0*w0, a1 = e1*w1, a2 = e2*w2, a3 = e3*w3;
  float2 f0 = *(const float2*)&hn[0*D + c];
  float2 f1 = *(const float2*)&hn[1*D + c];
  float2 f2 = *(const float2*)&hn[2*D + c];
  float2 f3 = *(const float2*)&hn[3*D + c];
  float ox = a0*f0.x + a1*f1.x + a2*f2.x + a3*f3.x;
  float oy = a0*f0.y + a1*f1.y + a2*f2.y + a3*f3.y;

  int j = beg;
  for (; j+1 < end; j += 2){
    int s0 = csr[j], s1 = csr[j+1];
    float4 as0 = *(const float4*)&a_src[s0*4];
    float4 as1 = *(const float4*)&a_src[s1*4];
    float b0 = __expf(lrelu(as0.x + ad.x))*w0;
    float b1 = __expf(lrelu(as0.y + ad.y))*w1;
    float b2 = __expf(lrelu(as0.z + ad.z))*w2;
    float b3 = __expf(lrelu(as0.w + ad.w))*w3;
    float c0 = __expf(lrelu(as1.x + ad.x))*w0;
    float c1 = __expf(lrelu(as1.y + ad.y))*w1;
    float c2 = __expf(lrelu(as1.z + ad.z))*w2;
    float c3 = __expf(lrelu(as1.w + ad.w))*w3;
    const float* h0 = &hg[s0*HD];
    const float* h1 = &hg[s1*HD];
    float2 g0 = *(const float2*)&h0[0*D + c];
    float2 g1 = *(const float2*)&h0[1*D + c];
    float2 g2 = *(const float2*)&h0[2*D + c];
    float2 g3 = *(const float2*)&h0[3*D + c];
    float2 k0 = *(const float2*)&h1[0*D + c];
    float2 k1 = *(const float2*)&h1[1*D + c];
    float2 k2 = *(const float2*)&h1[2*D + c];
    float2 k3 = *(const float2*)&h1[3*D + c];
    ox += b0*g0.x + b1*g1.x + b2*g2.x + b3*g3.x
        + c0*k0.x + c1*k1.x + c2*k2.x + c3*k3.x;
    oy += b0*g0.y + b1*g1.y + b2*g2.y + b3*g3.y
        + c0*k0.y + c1*k1.y + c2*k2.y + c3*k3.y;
  }
  if (j < end){
    int s0 = csr[j];
    float4 as0 = *(const float4*)&a_src[s0*4];
    float b0 = __expf(lrelu(as0.x + ad.x))*w0;
    float b1 = __expf(lrelu(as0.y + ad.y))*w1;
    float b2 = __expf(lrelu(as0.z + ad.z))*w2;
    float b3 = __expf(lrelu(as0.w + ad.w))*w3;
    const float* h0 = &hg[s0*HD];
    float2 g0 = *(const float2*)&h0[0*D + c];
    float2 g1 = *(const float2*)&h0[1*D + c];
    float2 g2 = *(const float2*)&h0[2*D + c];
    float2 g3 = *(const float2*)&h0[3*D + c];
    ox += b0*g0.x + b1*g1.x + b2*g2.x + b3*g3.x;
    oy += b0*g0.y + b1*g1.y + b2*g2.y + b3*g3.y;
  }
  out[w*D + c]     = fmaxf(ox + bias[c],   0.f);
  out[w*D + c + 1] = fmaxf(oy + bias[c+1], 0.f);
}

extern "C" void kernel_launch(void* const* d_in, const int* in_sizes, int n_in,
                              void* d_out, int out_size, void* d_ws, size_t ws_size,
                              hipStream_t stream){
  const float* x     = (const float*)d_in[0];
  const int*   ei    = (const int*)d_in[1];
  const float* gcn_w = (const float*)d_in[2];
  const float* gcn_b = (const float*)d_in[3];
  const float* gat_w = (const float*)d_in[4];
  const float* att_s = (const float*)d_in[5];
  const float* att_d = (const float*)d_in[6];
  const float* gat_b = (const float*)d_in[7];
  const float* w1    = (const float*)d_in[8];
  const float* b1    = (const float*)d_in[9];
  const float* w2    = (const float*)d_in[10];
  const float* b2    = (const float*)d_in[11];
  const float* mu_w  = (const float*)d_in[12];
  const float* mu_b  = (const float*)d_in[13];
  const float* lv_w  = (const float*)d_in[14];
  const float* lv_b  = (const float*)d_in[15];
  const int E = in_sizes[1] / 2;
  const int* src = ei;
  const int* dst = ei + E;

  float* ws    = (float*)d_ws;
  float* xw    = ws;                 // N*128 (later h3)
  float* h1    = xw + NN*D;          // N*128 (later h4)
  float* h2    = h1 + NN*D;          // N*128
  float* hg    = h2 + NN*D;          // N*512
  float* dinv  = hg + NN*HD;         // N
  float* a_src = dinv + NN;          // N*4
  float* a_dst = a_src + NN*NH;      // N*4
  int*   ioff  = (int*)(a_dst + NN*NH);  // N+1
  int*   icur  = ioff + NN + 1;          // N (also deg histogram)
  int*   csr   = icur + NN;              // E

  const int gN  = (NN + 255)/256;
  const int gE  = (E + 255)/256;
  const int gR  = (NN + 63)/64;
  const int gW  = (NN + 3)/4;        // wave-per-node kernels

  // CSR build
  k_zero_int<<<gN, 256, 0, stream>>>(icur, NN);
  k_hist<<<gE, 256, 0, stream>>>(dst, icur, E);
  k_scan<<<1, 1024, 0, stream>>>(icur, ioff);
  k_dinv<<<gN, 256, 0, stream>>>(ioff, dinv);
  k_fill<<<gE, 256, 0, stream>>>(src, dst, icur, csr, E);

  // GCN
  k_gemm<<<dim3(gR,2), 256, 0, stream>>>(x, gcn_w, D, nullptr, xw, D, NN, 0);
  k_gcn_agg<<<gW, 256, 0, stream>>>(xw, dinv, ioff, csr, gcn_b, h1);

  // GAT
  k_gemm<<<dim3(gR,8), 256, 0, stream>>>(h1, gat_w, HD, nullptr, hg, HD, NN, 0);
  k_att<<<(NN*NH + 3)/4, 256, 0, stream>>>(hg, att_s, att_d, a_src, a_dst);
  k_gat_agg<<<gW, 256, 0, stream>>>(hg, a_src, a_dst, ioff, csr, gat_b, h2);

  // MLP + heads
  k_gemm<<<dim3(gR,2), 256, 0, stream>>>(h2, w1, D, b1, xw, D, NN, 1);
  k_gemm<<<dim3(gR,2), 256, 0, stream>>>(xw, w2, D, b2, h1, D, NN, 1);
  float* out = (float*)d_out;
  k_gemm<<<dim3(gR,1), 256, 0, stream>>>(h1, mu_w, ZD, mu_b, out, ZD, NN, 0);
  k_gemm<<<dim3(gR,1), 256, 0, stream>>>(h1, lv_w, ZD, lv_b, out + NN*ZD, ZD, NN, 0);
}

// Round 5
// 250.986 us; speedup vs baseline: 5.0695x; 1.1301x over previous
//
#include <hip/hip_runtime.h>

#define NN 10000
#define D 128
#define NH 4
#define HD 512   // NH * D
#define ZD 64

__device__ __forceinline__ float lrelu(float x){ return x > 0.0f ? x : 0.2f*x; }

// ---------------- CSR build ----------------
__global__ __launch_bounds__(256) void k_zero_int(int* __restrict__ a, int n){
  int i = blockIdx.x*256 + threadIdx.x;
  if (i < n) a[i] = 0;
}

__global__ __launch_bounds__(256) void k_hist(const int* __restrict__ dst,
                                              int* __restrict__ deg, int E){
  int i = blockIdx.x*256 + threadIdx.x;
  if (i < E) atomicAdd(&deg[dst[i]], 1);
}

// single block of 1024: exclusive scan of deg -> ioff, cursor reset, dinv
__global__ __launch_bounds__(1024) void k_scan(int* __restrict__ deg,
                                               int* __restrict__ ioff,
                                               float* __restrict__ dinv){
  __shared__ int part[1024];
  const int tid = threadIdx.x;
  const int base = tid*10;
  int local[10]; int s = 0;
#pragma unroll
  for (int i=0;i<10;i++){
    int idx = base+i;
    int v = (idx < NN) ? deg[idx] : 0;
    if (idx < NN) dinv[idx] = rsqrtf(1.0f + (float)v);
    local[i] = s; s += v;
  }
  part[tid] = s;
  __syncthreads();
  for (int o=1;o<1024;o<<=1){
    int v = (tid>=o) ? part[tid-o] : 0;
    __syncthreads();
    part[tid] += v;
    __syncthreads();
  }
  int excl = part[tid] - s;
#pragma unroll
  for (int i=0;i<10;i++){
    int idx = base+i;
    if (idx < NN){
      int o = excl + local[i];
      ioff[idx] = o;
      deg[idx]  = o;    // cursor reset
    }
  }
  if (tid == 1023) ioff[NN] = part[1023];
}

__global__ __launch_bounds__(256) void k_fill(const int* __restrict__ src,
                                              const int* __restrict__ dst,
                                              int* __restrict__ cur,
                                              int* __restrict__ csr, int E){
  int i = blockIdx.x*256 + threadIdx.x;
  if (i >= E) return;
  int pos = atomicAdd(&cur[dst[i]], 1);
  csr[pos] = src[i];
}

// ---------------- GEMM (for GCN / GAT projections) ----------------
__global__ __launch_bounds__(256) void k_gemm(const float* __restrict__ A,
                                              const float* __restrict__ W, int ldw,
                                              const float* __restrict__ bias,
                                              float* __restrict__ C, int ldc,
                                              int nrows, int do_relu){
  __shared__ float As[64][132];
  __shared__ float Ws[128][68];
  const int tid  = threadIdx.x;
  const int row0 = blockIdx.x*64;
  const int col0 = blockIdx.y*64;
#pragma unroll
  for (int i=0;i<8;i++){
    int f  = tid + i*256;
    int r  = f >> 5;
    int k4 = (f & 31) << 2;
    int rr = row0 + r;
    float4 v = make_float4(0.f,0.f,0.f,0.f);
    if (rr < nrows) v = *(const float4*)&A[rr*D + k4];
    *(float4*)&As[r][k4] = v;
  }
#pragma unroll
  for (int i=0;i<8;i++){
    int f  = tid + i*256;
    int k  = f >> 4;
    int c4 = (f & 15) << 2;
    float4 v = *(const float4*)&W[k*ldw + col0 + c4];
    *(float4*)&Ws[k][c4] = v;
  }
  __syncthreads();
  const int tx = tid & 15, ty = tid >> 4;
  float acc[4][4] = {{0.f}};
#pragma unroll 4
  for (int k=0;k<128;k++){
    float4 w = *(const float4*)&Ws[k][tx<<2];
    float wv[4] = {w.x, w.y, w.z, w.w};
    float av[4];
#pragma unroll
    for (int i=0;i<4;i++) av[i] = As[(ty<<2)+i][k];
#pragma unroll
    for (int i=0;i<4;i++)
#pragma unroll
      for (int j=0;j<4;j++) acc[i][j] = fmaf(av[i], wv[j], acc[i][j]);
  }
#pragma unroll
  for (int i=0;i<4;i++){
    int r = row0 + (ty<<2) + i;
    if (r >= nrows) continue;
#pragma unroll
    for (int j=0;j<4;j++){
      int c = col0 + (tx<<2) + j;
      float v = acc[i][j];
      if (bias) v += bias[c];
      if (do_relu) v = fmaxf(v, 0.f);
      C[r*ldc + c] = v;
    }
  }
}

// ---------------- GCN gather: one wave per node, LDS-staged coefficients ----
__global__ __launch_bounds__(256) void k_gcn_agg(const float* __restrict__ xw,
                                                 const float* __restrict__ dinv,
                                                 const int* __restrict__ ioff,
                                                 const int* __restrict__ csr,
                                                 const float* __restrict__ bias,
                                                 float* __restrict__ out){
  __shared__ float2 snm[4][64];
  int wv = threadIdx.x >> 6;
  int w  = blockIdx.x*4 + wv;
  if (w >= NN) return;
  int lane = threadIdx.x & 63;
  int c = lane << 1;
  int beg = ioff[w], end = ioff[w+1];
  float din = dinv[w];
  float2 sv = *(const float2*)&xw[w*D + c];
  float ax = sv.x*din, ay = sv.y*din;
  for (int jb = beg; jb < end; jb += 64){
    int cnt = end - jb; if (cnt > 64) cnt = 64;
    if (lane < cnt){
      int s = csr[jb + lane];
      snm[wv][lane] = make_float2(dinv[s], __int_as_float(s));
    }
    __builtin_amdgcn_wave_barrier();
#pragma unroll 2
    for (int l=0; l<cnt; l++){
      float2 t = snm[wv][l];
      int ss = __float_as_int(t.y);
      float2 v = *(const float2*)&xw[ss*D + c];
      ax = fmaf(t.x, v.x, ax);
      ay = fmaf(t.x, v.y, ay);
    }
    __builtin_amdgcn_wave_barrier();
  }
  out[w*D + c]     = fmaxf(fmaf(ax, din, bias[c]),   0.f);
  out[w*D + c + 1] = fmaxf(fmaf(ay, din, bias[c+1]), 0.f);
}

// ---------------- GAT attention coefficients ----------------
__global__ __launch_bounds__(256) void k_att(const float* __restrict__ hg,
                                             const float* __restrict__ att_src,
                                             const float* __restrict__ att_dst,
                                             float* __restrict__ a_src,
                                             float* __restrict__ a_dst){
  int wi   = blockIdx.x*4 + (threadIdx.x >> 6);
  int lane = threadIdx.x & 63;
  if (wi >= NN*NH) return;
  int n = wi >> 2, h = wi & 3;
  const float* row = &hg[n*HD + h*D];
  const float* as  = &att_src[h*D];
  const float* ad  = &att_dst[h*D];
  float v0 = row[lane], v1 = row[lane+64];
  float s = v0*as[lane] + v1*as[lane+64];
  float d = v0*ad[lane] + v1*ad[lane+64];
#pragma unroll
  for (int off=32; off>0; off>>=1){
    s += __shfl_down(s, off);
    d += __shfl_down(d, off);
  }
  if (lane == 0){ a_src[wi] = s; a_dst[wi] = d; }
}

// ---------------- GAT gather: single pass, unnormalized + post-scale ------
__global__ __launch_bounds__(256) void k_gat_agg(const float* __restrict__ hg,
                                                 const float* __restrict__ a_src,
                                                 const float* __restrict__ a_dst,
                                                 const int* __restrict__ ioff,
                                                 const int* __restrict__ csr,
                                                 const float* __restrict__ bias,
                                                 float* __restrict__ out){
  __shared__ float4 sal[4][64];
  __shared__ int    ssr[4][64];
  int wv = threadIdx.x >> 6;
  int w  = blockIdx.x*4 + wv;
  if (w >= NN) return;
  int lane = threadIdx.x & 63;
  int c = lane << 1;
  int beg = ioff[w], end = ioff[w+1];
  float4 ad  = *(const float4*)&a_dst[w*4];
  float4 asn = *(const float4*)&a_src[w*4];
  float e0 = __expf(lrelu(asn.x + ad.x));
  float e1 = __expf(lrelu(asn.y + ad.y));
  float e2 = __expf(lrelu(asn.z + ad.z));
  float e3 = __expf(lrelu(asn.w + ad.w));
  // per-lane denominator PARTIALS (self-loop term added ONCE after the reduce)
  float den0=0.f, den1=0.f, den2=0.f, den3=0.f;
  const float* hn = &hg[w*HD];
  float2 f0 = *(const float2*)&hn[0*D + c];
  float2 f1 = *(const float2*)&hn[1*D + c];
  float2 f2 = *(const float2*)&hn[2*D + c];
  float2 f3 = *(const float2*)&hn[3*D + c];
  float ox0 = e0*f0.x, oy0 = e0*f0.y;
  float ox1 = e1*f1.x, oy1 = e1*f1.y;
  float ox2 = e2*f2.x, oy2 = e2*f2.y;
  float ox3 = e3*f3.x, oy3 = e3*f3.y;

  for (int jb = beg; jb < end; jb += 64){
    int cnt = end - jb; if (cnt > 64) cnt = 64;
    if (lane < cnt){
      int s = csr[jb + lane];
      float4 as = *(const float4*)&a_src[s*4];
      float g0 = __expf(lrelu(as.x + ad.x));
      float g1 = __expf(lrelu(as.y + ad.y));
      float g2 = __expf(lrelu(as.z + ad.z));
      float g3 = __expf(lrelu(as.w + ad.w));
      sal[wv][lane] = make_float4(g0,g1,g2,g3);
      ssr[wv][lane] = s;
      den0 += g0; den1 += g1; den2 += g2; den3 += g3;
    }
    __builtin_amdgcn_wave_barrier();
#pragma unroll 2
    for (int l=0; l<cnt; l++){
      float4 b = sal[wv][l];
      int ss = ssr[wv][l];
      const float* hs = &hg[ss*HD];
      float2 g0 = *(const float2*)&hs[0*D + c];
      float2 g1 = *(const float2*)&hs[1*D + c];
      float2 g2 = *(const float2*)&hs[2*D + c];
      float2 g3 = *(const float2*)&hs[3*D + c];
      ox0 = fmaf(b.x, g0.x, ox0); oy0 = fmaf(b.x, g0.y, oy0);
      ox1 = fmaf(b.y, g1.x, ox1); oy1 = fmaf(b.y, g1.y, oy1);
      ox2 = fmaf(b.z, g2.x, ox2); oy2 = fmaf(b.z, g2.y, oy2);
      ox3 = fmaf(b.w, g3.x, ox3); oy3 = fmaf(b.w, g3.y, oy3);
    }
    __builtin_amdgcn_wave_barrier();
  }
#pragma unroll
  for (int o=32; o>0; o>>=1){
    den0 += __shfl_xor(den0, o);
    den1 += __shfl_xor(den1, o);
    den2 += __shfl_xor(den2, o);
    den3 += __shfl_xor(den3, o);
  }
  den0 += e0; den1 += e1; den2 += e2; den3 += e3;   // self-loop, once
  float w0 = 0.25f/den0, w1 = 0.25f/den1, w2 = 0.25f/den2, w3 = 0.25f/den3;
  float ox = ox0*w0 + ox1*w1 + ox2*w2 + ox3*w3;
  float oy = oy0*w0 + oy1*w1 + oy2*w2 + oy3*w3;
  out[w*D + c]     = fmaxf(ox + bias[c],   0.f);
  out[w*D + c + 1] = fmaxf(oy + bias[c+1], 0.f);
}

// ---------------- Fused MLP + heads ----------------
// h2 -> relu(@w1+b1) -> relu(@w2+b2) -> [mu|lv] -> out
__global__ __launch_bounds__(256) void k_mlp(const float* __restrict__ h2,
                                             const float* __restrict__ w1,
                                             const float* __restrict__ b1,
                                             const float* __restrict__ w2,
                                             const float* __restrict__ b2,
                                             const float* __restrict__ wmu,
                                             const float* __restrict__ bmu,
                                             const float* __restrict__ wlv,
                                             const float* __restrict__ blv,
                                             float* __restrict__ out){
  __shared__ float hA[64][132];
  __shared__ float hB[64][132];
  __shared__ float Ws[128][68];
  const int tid  = threadIdx.x;
  const int row0 = blockIdx.x*64;
  const int tx = tid & 15, ty = tid >> 4;

  // load h2 tile
#pragma unroll
  for (int i=0;i<8;i++){
    int f  = tid + i*256;
    int r  = f >> 5;
    int k4 = (f & 31) << 2;
    int rr = row0 + r;
    float4 v = make_float4(0.f,0.f,0.f,0.f);
    if (rr < NN) v = *(const float4*)&h2[rr*D + k4];
    *(float4*)&hA[r][k4] = v;
  }

  float (*S)[132] = hA;
  float (*T)[132] = hB;
#pragma unroll
  for (int layer=0; layer<2; layer++){
    const float* W  = layer ? w2 : w1;
    const float* bb = layer ? b2 : b1;
    for (int cc=0; cc<2; cc++){
      __syncthreads();
      // FIX: Ws is 128 rows x 16 float4 = 2048 float4 -> needs 8 iters of 256
#pragma unroll
      for (int i=0;i<8;i++){
        int f  = tid + i*256;      // 0..2047
        int k  = f >> 4;           // 0..127
        int c4 = (f & 15) << 2;    // 0..60
        *(float4*)&Ws[k][c4] = *(const float4*)&W[k*D + cc*64 + c4];
      }
      __syncthreads();
      float acc[4][4] = {{0.f}};
#pragma unroll 4
      for (int k=0;k<128;k++){
        float4 wvv = *(const float4*)&Ws[k][tx<<2];
        float wv[4] = {wvv.x, wvv.y, wvv.z, wvv.w};
        float av[4];
#pragma unroll
        for (int i=0;i<4;i++) av[i] = S[(ty<<2)+i][k];
#pragma unroll
        for (int i=0;i<4;i++)
#pragma unroll
          for (int j=0;j<4;j++) acc[i][j] = fmaf(av[i], wv[j], acc[i][j]);
      }
#pragma unroll
      for (int i=0;i<4;i++)
#pragma unroll
        for (int j=0;j<4;j++){
          int col = cc*64 + (tx<<2) + j;
          T[(ty<<2)+i][col] = fmaxf(acc[i][j] + bb[col], 0.f);
        }
    }
    // swap
    float (*tmp)[132] = S; S = T; T = tmp;
  }
  // heads: cc=0 -> mu, cc=1 -> lv
  for (int cc=0; cc<2; cc++){
    const float* W  = cc ? wlv : wmu;
    const float* bb = cc ? blv : bmu;
    float* ob = out + (size_t)cc*NN*ZD;
    __syncthreads();
    // FIX: 8 iterations here too (128 rows x 16 float4)
#pragma unroll
    for (int i=0;i<8;i++){
      int f  = tid + i*256;
      int k  = f >> 4;
      int c4 = (f & 15) << 2;
      *(float4*)&Ws[k][c4] = *(const float4*)&W[k*ZD + c4];
    }
    __syncthreads();
    float acc[4][4] = {{0.f}};
#pragma unroll 4
    for (int k=0;k<128;k++){
      float4 wvv = *(const float4*)&Ws[k][tx<<2];
      float wv[4] = {wvv.x, wvv.y, wvv.z, wvv.w};
      float av[4];
#pragma unroll
      for (int i=0;i<4;i++) av[i] = S[(ty<<2)+i][k];
#pragma unroll
      for (int i=0;i<4;i++)
#pragma unroll
        for (int j=0;j<4;j++) acc[i][j] = fmaf(av[i], wv[j], acc[i][j]);
    }
#pragma unroll
    for (int i=0;i<4;i++){
      int r = row0 + (ty<<2) + i;
      if (r >= NN) continue;
      float4 v = make_float4(acc[i][0] + bb[(tx<<2)+0],
                             acc[i][1] + bb[(tx<<2)+1],
                             acc[i][2] + bb[(tx<<2)+2],
                             acc[i][3] + bb[(tx<<2)+3]);
      *(float4*)&ob[r*ZD + (tx<<2)] = v;
    }
  }
}

extern "C" void kernel_launch(void* const* d_in, const int* in_sizes, int n_in,
                              void* d_out, int out_size, void* d_ws, size_t ws_size,
                              hipStream_t stream){
  const float* x     = (const float*)d_in[0];
  const int*   ei    = (const int*)d_in[1];
  const float* gcn_w = (const float*)d_in[2];
  const float* gcn_b = (const float*)d_in[3];
  const float* gat_w = (const float*)d_in[4];
  const float* att_s = (const float*)d_in[5];
  const float* att_d = (const float*)d_in[6];
  const float* gat_b = (const float*)d_in[7];
  const float* w1    = (const float*)d_in[8];
  const float* b1    = (const float*)d_in[9];
  const float* w2    = (const float*)d_in[10];
  const float* b2    = (const float*)d_in[11];
  const float* mu_w  = (const float*)d_in[12];
  const float* mu_b  = (const float*)d_in[13];
  const float* lv_w  = (const float*)d_in[14];
  const float* lv_b  = (const float*)d_in[15];
  const int E = in_sizes[1] / 2;
  const int* src = ei;
  const int* dst = ei + E;

  float* ws    = (float*)d_ws;
  float* xw    = ws;                 // N*128
  float* h1    = xw + NN*D;          // N*128
  float* h2    = h1 + NN*D;          // N*128
  float* hg    = h2 + NN*D;          // N*512
  float* dinv  = hg + NN*HD;         // N
  float* a_src = dinv + NN;          // N*4
  float* a_dst = a_src + NN*NH;      // N*4
  int*   ioff  = (int*)(a_dst + NN*NH);  // N+1
  int*   icur  = ioff + NN + 1;          // N
  int*   csr   = icur + NN;              // E

  const int gN = (NN + 255)/256;
  const int gE = (E + 255)/256;
  const int gR = (NN + 63)/64;
  const int gW = (NN + 3)/4;

  // CSR build
  k_zero_int<<<gN, 256, 0, stream>>>(icur, NN);
  k_hist<<<gE, 256, 0, stream>>>(dst, icur, E);
  k_scan<<<1, 1024, 0, stream>>>(icur, ioff, dinv);
  k_fill<<<gE, 256, 0, stream>>>(src, dst, icur, csr, E);

  // GCN
  k_gemm<<<dim3(gR,2), 256, 0, stream>>>(x, gcn_w, D, nullptr, xw, D, NN, 0);
  k_gcn_agg<<<gW, 256, 0, stream>>>(xw, dinv, ioff, csr, gcn_b, h1);

  // GAT
  k_gemm<<<dim3(gR,8), 256, 0, stream>>>(h1, gat_w, HD, nullptr, hg, HD, NN, 0);
  k_att<<<(NN*NH + 3)/4, 256, 0, stream>>>(hg, att_s, att_d, a_src, a_dst);
  k_gat_agg<<<gW, 256, 0, stream>>>(hg, a_src, a_dst, ioff, csr, gat_b, h2);

  // MLP + heads fused
  k_mlp<<<gR, 256, 0, stream>>>(h2, w1, b1, w2, b2, mu_w, mu_b, lv_w, lv_b,
                                (float*)d_out);
}

// Round 6
// 239.153 us; speedup vs baseline: 5.3203x; 1.0495x over previous
//
#include <hip/hip_runtime.h>

#define NN 10000
#define D 128
#define NH 4
#define HD 512   // NH * D
#define ZD 64

__device__ __forceinline__ float lrelu(float x){ return x > 0.0f ? x : 0.2f*x; }

// ---------------- CSR build ----------------
__global__ __launch_bounds__(256) void k_zero_int(int* __restrict__ a, int n){
  int i = blockIdx.x*256 + threadIdx.x;
  if (i < n) a[i] = 0;
}

__global__ __launch_bounds__(256) void k_hist(const int* __restrict__ dst,
                                              int* __restrict__ deg, int E){
  int i = blockIdx.x*256 + threadIdx.x;
  if (i < E) atomicAdd(&deg[dst[i]], 1);
}

// single block of 1024: exclusive scan of deg -> ioff, cursor reset, dinv
__global__ __launch_bounds__(1024) void k_scan(int* __restrict__ deg,
                                               int* __restrict__ ioff,
                                               float* __restrict__ dinv){
  __shared__ int part[1024];
  const int tid = threadIdx.x;
  const int base = tid*10;
  int local[10]; int s = 0;
#pragma unroll
  for (int i=0;i<10;i++){
    int idx = base+i;
    int v = (idx < NN) ? deg[idx] : 0;
    if (idx < NN) dinv[idx] = rsqrtf(1.0f + (float)v);
    local[i] = s; s += v;
  }
  part[tid] = s;
  __syncthreads();
  for (int o=1;o<1024;o<<=1){
    int v = (tid>=o) ? part[tid-o] : 0;
    __syncthreads();
    part[tid] += v;
    __syncthreads();
  }
  int excl = part[tid] - s;
#pragma unroll
  for (int i=0;i<10;i++){
    int idx = base+i;
    if (idx < NN){
      int o = excl + local[i];
      ioff[idx] = o;
      deg[idx]  = o;    // cursor reset
    }
  }
  if (tid == 1023) ioff[NN] = part[1023];
}

// fill CSR; also zero a_src/a_dst (contiguous, NN*NH*2 floats) for the
// gemm_att epilogue atomics
__global__ __launch_bounds__(256) void k_fill(const int* __restrict__ src,
                                              const int* __restrict__ dst,
                                              int* __restrict__ cur,
                                              int* __restrict__ csr, int E,
                                              float* __restrict__ az){
  int i = blockIdx.x*256 + threadIdx.x;
  if (i < NN*NH*2) az[i] = 0.f;
  if (i >= E) return;
  int pos = atomicAdd(&cur[dst[i]], 1);
  csr[pos] = src[i];
}

// ---------------- generic GEMM (GCN projection) ----------------
__global__ __launch_bounds__(256) void k_gemm(const float* __restrict__ A,
                                              const float* __restrict__ W, int ldw,
                                              const float* __restrict__ bias,
                                              float* __restrict__ C, int ldc,
                                              int nrows, int do_relu){
  __shared__ float As[64][132];
  __shared__ float Ws[128][68];
  const int tid  = threadIdx.x;
  const int row0 = blockIdx.x*64;
  const int col0 = blockIdx.y*64;
#pragma unroll
  for (int i=0;i<8;i++){
    int f  = tid + i*256;
    int r  = f >> 5;
    int k4 = (f & 31) << 2;
    int rr = row0 + r;
    float4 v = make_float4(0.f,0.f,0.f,0.f);
    if (rr < nrows) v = *(const float4*)&A[rr*D + k4];
    *(float4*)&As[r][k4] = v;
  }
#pragma unroll
  for (int i=0;i<8;i++){
    int f  = tid + i*256;
    int k  = f >> 4;
    int c4 = (f & 15) << 2;
    float4 v = *(const float4*)&W[k*ldw + col0 + c4];
    *(float4*)&Ws[k][c4] = v;
  }
  __syncthreads();
  const int tx = tid & 15, ty = tid >> 4;
  float acc[4][4] = {{0.f}};
#pragma unroll 4
  for (int k=0;k<128;k++){
    float4 w = *(const float4*)&Ws[k][tx<<2];
    float wv[4] = {w.x, w.y, w.z, w.w};
    float av[4];
#pragma unroll
    for (int i=0;i<4;i++) av[i] = As[(ty<<2)+i][k];
#pragma unroll
    for (int i=0;i<4;i++)
#pragma unroll
      for (int j=0;j<4;j++) acc[i][j] = fmaf(av[i], wv[j], acc[i][j]);
  }
#pragma unroll
  for (int i=0;i<4;i++){
    int r = row0 + (ty<<2) + i;
    if (r >= nrows) continue;
#pragma unroll
    for (int j=0;j<4;j++){
      int c = col0 + (tx<<2) + j;
      float v = acc[i][j];
      if (bias) v += bias[c];
      if (do_relu) v = fmaxf(v, 0.f);
      C[r*ldc + c] = v;
    }
  }
}

// ---------------- GAT GEMM with fused attention-coefficient epilogue -------
// hg = h1 @ gat_w (no bias/relu); per 64x64 tile also accumulate partial
// a_src/a_dst dot products (16-lane shfl reduce + atomicAdd).
__global__ __launch_bounds__(256) void k_gemm_att(const float* __restrict__ A,
                                                  const float* __restrict__ W,
                                                  float* __restrict__ C,
                                                  const float* __restrict__ att_src,
                                                  const float* __restrict__ att_dst,
                                                  float* __restrict__ a_src,
                                                  float* __restrict__ a_dst){
  __shared__ float As[64][132];
  __shared__ float Ws[128][68];
  const int tid  = threadIdx.x;
  const int row0 = blockIdx.x*64;
  const int col0 = blockIdx.y*64;
#pragma unroll
  for (int i=0;i<8;i++){
    int f  = tid + i*256;
    int r  = f >> 5;
    int k4 = (f & 31) << 2;
    int rr = row0 + r;
    float4 v = make_float4(0.f,0.f,0.f,0.f);
    if (rr < NN) v = *(const float4*)&A[rr*D + k4];
    *(float4*)&As[r][k4] = v;
  }
#pragma unroll
  for (int i=0;i<8;i++){
    int f  = tid + i*256;
    int k  = f >> 4;
    int c4 = (f & 15) << 2;
    *(float4*)&Ws[k][c4] = *(const float4*)&W[k*HD + col0 + c4];
  }
  __syncthreads();
  const int tx = tid & 15, ty = tid >> 4;
  float acc[4][4] = {{0.f}};
#pragma unroll 4
  for (int k=0;k<128;k++){
    float4 w = *(const float4*)&Ws[k][tx<<2];
    float wv[4] = {w.x, w.y, w.z, w.w};
    float av[4];
#pragma unroll
    for (int i=0;i<4;i++) av[i] = As[(ty<<2)+i][k];
#pragma unroll
    for (int i=0;i<4;i++)
#pragma unroll
      for (int j=0;j<4;j++) acc[i][j] = fmaf(av[i], wv[j], acc[i][j]);
  }
#pragma unroll
  for (int i=0;i<4;i++){
    int r = row0 + (ty<<2) + i;
    if (r >= NN) continue;
#pragma unroll
    for (int j=0;j<4;j++)
      C[r*HD + col0 + (tx<<2) + j] = acc[i][j];
  }
  // fused attention partial dots over this tile's 64 columns (one head)
  const int h = col0 >> 7;
  const int cb = (col0 & 127) + (tx<<2);
  float ps[4], pd[4];
#pragma unroll
  for (int i=0;i<4;i++){
    float s_ = 0.f, d_ = 0.f;
#pragma unroll
    for (int j=0;j<4;j++){
      s_ = fmaf(acc[i][j], att_src[h*D + cb + j], s_);
      d_ = fmaf(acc[i][j], att_dst[h*D + cb + j], d_);
    }
    ps[i] = s_; pd[i] = d_;
  }
#pragma unroll
  for (int o=8;o>0;o>>=1){
#pragma unroll
    for (int i=0;i<4;i++){
      ps[i] += __shfl_xor(ps[i], o);
      pd[i] += __shfl_xor(pd[i], o);
    }
  }
  if (tx == 0){
#pragma unroll
    for (int i=0;i<4;i++){
      int r = row0 + (ty<<2) + i;
      if (r < NN){
        atomicAdd(&a_src[r*4 + h], ps[i]);
        atomicAdd(&a_dst[r*4 + h], pd[i]);
      }
    }
  }
}

// ---------------- GCN gather: one wave per node, LDS-staged coefficients ----
__global__ __launch_bounds__(256) void k_gcn_agg(const float* __restrict__ xw,
                                                 const float* __restrict__ dinv,
                                                 const int* __restrict__ ioff,
                                                 const int* __restrict__ csr,
                                                 const float* __restrict__ bias,
                                                 float* __restrict__ out){
  __shared__ float2 snm[4][64];
  int wv = threadIdx.x >> 6;
  int w  = blockIdx.x*4 + wv;
  if (w >= NN) return;
  int lane = threadIdx.x & 63;
  int c = lane << 1;
  int beg = ioff[w], end = ioff[w+1];
  float din = dinv[w];
  float2 sv = *(const float2*)&xw[w*D + c];
  float ax = sv.x*din, ay = sv.y*din;
  for (int jb = beg; jb < end; jb += 64){
    int cnt = end - jb; if (cnt > 64) cnt = 64;
    if (lane < cnt){
      int s = csr[jb + lane];
      snm[wv][lane] = make_float2(dinv[s], __int_as_float(s));
    }
    __builtin_amdgcn_wave_barrier();
#pragma unroll 4
    for (int l=0; l<cnt; l++){
      float2 t = snm[wv][l];
      int ss = __float_as_int(t.y);
      float2 v = *(const float2*)&xw[ss*D + c];
      ax = fmaf(t.x, v.x, ax);
      ay = fmaf(t.x, v.y, ay);
    }
    __builtin_amdgcn_wave_barrier();
  }
  out[w*D + c]     = fmaxf(fmaf(ax, din, bias[c]),   0.f);
  out[w*D + c + 1] = fmaxf(fmaf(ay, din, bias[c+1]), 0.f);
}

// ---------------- GAT gather: 2 waves per node (head-pair split) ----------
// block = 256 thr = 4 waves = 2 nodes x 2 head-pairs; grid = NN/2 (NN even)
__global__ __launch_bounds__(256) void k_gat_agg(const float* __restrict__ hg,
                                                 const float* __restrict__ a_src,
                                                 const float* __restrict__ a_dst,
                                                 const int* __restrict__ ioff,
                                                 const int* __restrict__ csr,
                                                 const float* __restrict__ bias,
                                                 float* __restrict__ out){
  __shared__ float2 sal[4][64];
  __shared__ int    ssr[4][64];
  __shared__ float  part[2][128];
  const int wv   = threadIdx.x >> 6;       // 0..3
  const int nl   = wv >> 1;                // node within block
  const int hp   = (wv & 1) << 1;          // head pair base: 0 or 2
  const int w    = blockIdx.x*2 + nl;      // node id, always < NN
  const int lane = threadIdx.x & 63;
  const int c    = lane << 1;
  const int beg = ioff[w], end = ioff[w+1];
  float2 ad  = *(const float2*)&a_dst[w*4 + hp];
  float2 asn = *(const float2*)&a_src[w*4 + hp];
  float e0 = __expf(lrelu(asn.x + ad.x));
  float e1 = __expf(lrelu(asn.y + ad.y));
  float den0 = 0.f, den1 = 0.f;            // self term added once after reduce
  const float* hn = &hg[w*HD + hp*D];
  float2 f0 = *(const float2*)&hn[c];
  float2 f1 = *(const float2*)&hn[D + c];
  float ox0 = e0*f0.x, oy0 = e0*f0.y;
  float ox1 = e1*f1.x, oy1 = e1*f1.y;

  for (int jb = beg; jb < end; jb += 64){
    int cnt = end - jb; if (cnt > 64) cnt = 64;
    if (lane < cnt){
      int s = csr[jb + lane];
      float2 as = *(const float2*)&a_src[s*4 + hp];
      float g0 = __expf(lrelu(as.x + ad.x));
      float g1 = __expf(lrelu(as.y + ad.y));
      sal[wv][lane] = make_float2(g0, g1);
      ssr[wv][lane] = s;
      den0 += g0; den1 += g1;
    }
    __builtin_amdgcn_wave_barrier();
#pragma unroll 4
    for (int l=0; l<cnt; l++){
      float2 b = sal[wv][l];
      const float* hs = &hg[ssr[wv][l]*HD + hp*D];
      float2 g0 = *(const float2*)&hs[c];
      float2 g1 = *(const float2*)&hs[D + c];
      ox0 = fmaf(b.x, g0.x, ox0); oy0 = fmaf(b.x, g0.y, oy0);
      ox1 = fmaf(b.y, g1.x, ox1); oy1 = fmaf(b.y, g1.y, oy1);
    }
    __builtin_amdgcn_wave_barrier();
  }
#pragma unroll
  for (int o=32; o>0; o>>=1){
    den0 += __shfl_xor(den0, o);
    den1 += __shfl_xor(den1, o);
  }
  den0 += e0; den1 += e1;
  float w0 = 0.25f/den0, w1 = 0.25f/den1;
  float ox = ox0*w0 + ox1*w1;
  float oy = oy0*w0 + oy1*w1;
  if (hp){ part[nl][c] = ox; part[nl][c+1] = oy; }
  __syncthreads();
  if (!hp){
    ox += part[nl][c];
    oy += part[nl][c+1];
    out[w*D + c]     = fmaxf(ox + bias[c],   0.f);
    out[w*D + c + 1] = fmaxf(oy + bias[c+1], 0.f);
  }
}

// ---------------- Fused MLP + heads ----------------
__global__ __launch_bounds__(256) void k_mlp(const float* __restrict__ h2,
                                             const float* __restrict__ w1,
                                             const float* __restrict__ b1,
                                             const float* __restrict__ w2,
                                             const float* __restrict__ b2,
                                             const float* __restrict__ wmu,
                                             const float* __restrict__ bmu,
                                             const float* __restrict__ wlv,
                                             const float* __restrict__ blv,
                                             float* __restrict__ out){
  __shared__ float hA[64][132];
  __shared__ float hB[64][132];
  __shared__ float Ws[128][68];
  const int tid  = threadIdx.x;
  const int row0 = blockIdx.x*64;
  const int tx = tid & 15, ty = tid >> 4;

#pragma unroll
  for (int i=0;i<8;i++){
    int f  = tid + i*256;
    int r  = f >> 5;
    int k4 = (f & 31) << 2;
    int rr = row0 + r;
    float4 v = make_float4(0.f,0.f,0.f,0.f);
    if (rr < NN) v = *(const float4*)&h2[rr*D + k4];
    *(float4*)&hA[r][k4] = v;
  }

  float (*S)[132] = hA;
  float (*T)[132] = hB;
#pragma unroll
  for (int layer=0; layer<2; layer++){
    const float* W  = layer ? w2 : w1;
    const float* bb = layer ? b2 : b1;
    for (int cc=0; cc<2; cc++){
      __syncthreads();
#pragma unroll
      for (int i=0;i<8;i++){
        int f  = tid + i*256;
        int k  = f >> 4;
        int c4 = (f & 15) << 2;
        *(float4*)&Ws[k][c4] = *(const float4*)&W[k*D + cc*64 + c4];
      }
      __syncthreads();
      float acc[4][4] = {{0.f}};
#pragma unroll 4
      for (int k=0;k<128;k++){
        float4 wvv = *(const float4*)&Ws[k][tx<<2];
        float wv[4] = {wvv.x, wvv.y, wvv.z, wvv.w};
        float av[4];
#pragma unroll
        for (int i=0;i<4;i++) av[i] = S[(ty<<2)+i][k];
#pragma unroll
        for (int i=0;i<4;i++)
#pragma unroll
          for (int j=0;j<4;j++) acc[i][j] = fmaf(av[i], wv[j], acc[i][j]);
      }
#pragma unroll
      for (int i=0;i<4;i++)
#pragma unroll
        for (int j=0;j<4;j++){
          int col = cc*64 + (tx<<2) + j;
          T[(ty<<2)+i][col] = fmaxf(acc[i][j] + bb[col], 0.f);
        }
    }
    float (*tmp)[132] = S; S = T; T = tmp;
  }
  for (int cc=0; cc<2; cc++){
    const float* W  = cc ? wlv : wmu;
    const float* bb = cc ? blv : bmu;
    float* ob = out + (size_t)cc*NN*ZD;
    __syncthreads();
#pragma unroll
    for (int i=0;i<8;i++){
      int f  = tid + i*256;
      int k  = f >> 4;
      int c4 = (f & 15) << 2;
      *(float4*)&Ws[k][c4] = *(const float4*)&W[k*ZD + c4];
    }
    __syncthreads();
    float acc[4][4] = {{0.f}};
#pragma unroll 4
    for (int k=0;k<128;k++){
      float4 wvv = *(const float4*)&Ws[k][tx<<2];
      float wv[4] = {wvv.x, wvv.y, wvv.z, wvv.w};
      float av[4];
#pragma unroll
      for (int i=0;i<4;i++) av[i] = S[(ty<<2)+i][k];
#pragma unroll
      for (int i=0;i<4;i++)
#pragma unroll
        for (int j=0;j<4;j++) acc[i][j] = fmaf(av[i], wv[j], acc[i][j]);
    }
#pragma unroll
    for (int i=0;i<4;i++){
      int r = row0 + (ty<<2) + i;
      if (r >= NN) continue;
      float4 v = make_float4(acc[i][0] + bb[(tx<<2)+0],
                             acc[i][1] + bb[(tx<<2)+1],
                             acc[i][2] + bb[(tx<<2)+2],
                             acc[i][3] + bb[(tx<<2)+3]);
      *(float4*)&ob[r*ZD + (tx<<2)] = v;
    }
  }
}

extern "C" void kernel_launch(void* const* d_in, const int* in_sizes, int n_in,
                              void* d_out, int out_size, void* d_ws, size_t ws_size,
                              hipStream_t stream){
  const float* x     = (const float*)d_in[0];
  const int*   ei    = (const int*)d_in[1];
  const float* gcn_w = (const float*)d_in[2];
  const float* gcn_b = (const float*)d_in[3];
  const float* gat_w = (const float*)d_in[4];
  const float* att_s = (const float*)d_in[5];
  const float* att_d = (const float*)d_in[6];
  const float* gat_b = (const float*)d_in[7];
  const float* w1    = (const float*)d_in[8];
  const float* b1    = (const float*)d_in[9];
  const float* w2    = (const float*)d_in[10];
  const float* b2    = (const float*)d_in[11];
  const float* mu_w  = (const float*)d_in[12];
  const float* mu_b  = (const float*)d_in[13];
  const float* lv_w  = (const float*)d_in[14];
  const float* lv_b  = (const float*)d_in[15];
  const int E = in_sizes[1] / 2;
  const int* src = ei;
  const int* dst = ei + E;

  float* ws    = (float*)d_ws;
  float* xw    = ws;                 // N*128
  float* h1    = xw + NN*D;          // N*128
  float* h2    = h1 + NN*D;          // N*128
  float* hg    = h2 + NN*D;          // N*512
  float* dinv  = hg + NN*HD;         // N
  float* a_src = dinv + NN;          // N*4
  float* a_dst = a_src + NN*NH;      // N*4 (contiguous with a_src)
  int*   ioff  = (int*)(a_dst + NN*NH);  // N+1
  int*   icur  = ioff + NN + 1;          // N
  int*   csr   = icur + NN;              // E

  const int gN = (NN + 255)/256;
  const int gE = (E + 255)/256;
  const int gR = (NN + 63)/64;
  const int gW = (NN + 3)/4;

  // CSR build (+ zero a_src/a_dst for the gemm_att epilogue atomics)
  k_zero_int<<<gN, 256, 0, stream>>>(icur, NN);
  k_hist<<<gE, 256, 0, stream>>>(dst, icur, E);
  k_scan<<<1, 1024, 0, stream>>>(icur, ioff, dinv);
  k_fill<<<gE, 256, 0, stream>>>(src, dst, icur, csr, E, a_src);

  // GCN
  k_gemm<<<dim3(gR,2), 256, 0, stream>>>(x, gcn_w, D, nullptr, xw, D, NN, 0);
  k_gcn_agg<<<gW, 256, 0, stream>>>(xw, dinv, ioff, csr, gcn_b, h1);

  // GAT (projection + fused attention coefficients)
  k_gemm_att<<<dim3(gR,8), 256, 0, stream>>>(h1, gat_w, hg, att_s, att_d,
                                             a_src, a_dst);
  k_gat_agg<<<NN/2, 256, 0, stream>>>(hg, a_src, a_dst, ioff, csr, gat_b, h2);

  // MLP + heads fused
  k_mlp<<<gR, 256, 0, stream>>>(h2, w1, b1, w2, b2, mu_w, mu_b, lv_w, lv_b,
                                (float*)d_out);
}

// Round 7
// 208.445 us; speedup vs baseline: 6.1041x; 1.1473x over previous
//
#include <hip/hip_runtime.h>

#define NN 10000
#define D 128
#define NH 4
#define HD 512   // NH * D
#define ZD 64

__device__ __forceinline__ float lrelu(float x){ return x > 0.0f ? x : 0.2f*x; }

// ---------------- CSR build ----------------
__global__ __launch_bounds__(256) void k_zero_int(int* __restrict__ a, int n){
  int i = blockIdx.x*256 + threadIdx.x;
  if (i < n) a[i] = 0;
}

__global__ __launch_bounds__(256) void k_hist(const int* __restrict__ dst,
                                              int* __restrict__ deg, int E){
  int i = blockIdx.x*256 + threadIdx.x;
  if (i < E) atomicAdd(&deg[dst[i]], 1);
}

// single block of 1024: exclusive scan of deg -> ioff, cursor reset, dinv
__global__ __launch_bounds__(1024) void k_scan(int* __restrict__ deg,
                                               int* __restrict__ ioff,
                                               float* __restrict__ dinv){
  __shared__ int part[1024];
  const int tid = threadIdx.x;
  const int base = tid*10;
  int local[10]; int s = 0;
#pragma unroll
  for (int i=0;i<10;i++){
    int idx = base+i;
    int v = (idx < NN) ? deg[idx] : 0;
    if (idx < NN) dinv[idx] = rsqrtf(1.0f + (float)v);
    local[i] = s; s += v;
  }
  part[tid] = s;
  __syncthreads();
  for (int o=1;o<1024;o<<=1){
    int v = (tid>=o) ? part[tid-o] : 0;
    __syncthreads();
    part[tid] += v;
    __syncthreads();
  }
  int excl = part[tid] - s;
#pragma unroll
  for (int i=0;i<10;i++){
    int idx = base+i;
    if (idx < NN){
      int o = excl + local[i];
      ioff[idx] = o;
      deg[idx]  = o;    // cursor reset
    }
  }
  if (tid == 1023) ioff[NN] = part[1023];
}

// fill CSR; also zero a_src/a_dst (contiguous) for gemm_att epilogue atomics
__global__ __launch_bounds__(256) void k_fill(const int* __restrict__ src,
                                              const int* __restrict__ dst,
                                              int* __restrict__ cur,
                                              int* __restrict__ csr, int E,
                                              float* __restrict__ az){
  int i = blockIdx.x*256 + threadIdx.x;
  if (i < NN*NH*2) az[i] = 0.f;
  if (i >= E) return;
  int pos = atomicAdd(&cur[dst[i]], 1);
  csr[pos] = src[i];
}

// ---------------- generic GEMM (GCN projection) ----------------
__global__ __launch_bounds__(256) void k_gemm(const float* __restrict__ A,
                                              const float* __restrict__ W, int ldw,
                                              const float* __restrict__ bias,
                                              float* __restrict__ C, int ldc,
                                              int nrows, int do_relu){
  __shared__ float As[64][132];
  __shared__ float Ws[128][68];
  const int tid  = threadIdx.x;
  const int row0 = blockIdx.x*64;
  const int col0 = blockIdx.y*64;
#pragma unroll
  for (int i=0;i<8;i++){
    int f  = tid + i*256;
    int r  = f >> 5;
    int k4 = (f & 31) << 2;
    int rr = row0 + r;
    float4 v = make_float4(0.f,0.f,0.f,0.f);
    if (rr < nrows) v = *(const float4*)&A[rr*D + k4];
    *(float4*)&As[r][k4] = v;
  }
#pragma unroll
  for (int i=0;i<8;i++){
    int f  = tid + i*256;
    int k  = f >> 4;
    int c4 = (f & 15) << 2;
    float4 v = *(const float4*)&W[k*ldw + col0 + c4];
    *(float4*)&Ws[k][c4] = v;
  }
  __syncthreads();
  const int tx = tid & 15, ty = tid >> 4;
  float acc[4][4] = {{0.f}};
#pragma unroll 4
  for (int k=0;k<128;k++){
    float4 w = *(const float4*)&Ws[k][tx<<2];
    float wv[4] = {w.x, w.y, w.z, w.w};
    float av[4];
#pragma unroll
    for (int i=0;i<4;i++) av[i] = As[(ty<<2)+i][k];
#pragma unroll
    for (int i=0;i<4;i++)
#pragma unroll
      for (int j=0;j<4;j++) acc[i][j] = fmaf(av[i], wv[j], acc[i][j]);
  }
#pragma unroll
  for (int i=0;i<4;i++){
    int r = row0 + (ty<<2) + i;
    if (r >= nrows) continue;
#pragma unroll
    for (int j=0;j<4;j++){
      int c = col0 + (tx<<2) + j;
      float v = acc[i][j];
      if (bias) v += bias[c];
      if (do_relu) v = fmaxf(v, 0.f);
      C[r*ldc + c] = v;
    }
  }
}

// ---------------- GAT GEMM with fused attention-coefficient epilogue -------
__global__ __launch_bounds__(256) void k_gemm_att(const float* __restrict__ A,
                                                  const float* __restrict__ W,
                                                  float* __restrict__ C,
                                                  const float* __restrict__ att_src,
                                                  const float* __restrict__ att_dst,
                                                  float* __restrict__ a_src,
                                                  float* __restrict__ a_dst){
  __shared__ float As[64][132];
  __shared__ float Ws[128][68];
  const int tid  = threadIdx.x;
  const int row0 = blockIdx.x*64;
  const int col0 = blockIdx.y*64;
#pragma unroll
  for (int i=0;i<8;i++){
    int f  = tid + i*256;
    int r  = f >> 5;
    int k4 = (f & 31) << 2;
    int rr = row0 + r;
    float4 v = make_float4(0.f,0.f,0.f,0.f);
    if (rr < NN) v = *(const float4*)&A[rr*D + k4];
    *(float4*)&As[r][k4] = v;
  }
#pragma unroll
  for (int i=0;i<8;i++){
    int f  = tid + i*256;
    int k  = f >> 4;
    int c4 = (f & 15) << 2;
    *(float4*)&Ws[k][c4] = *(const float4*)&W[k*HD + col0 + c4];
  }
  __syncthreads();
  const int tx = tid & 15, ty = tid >> 4;
  float acc[4][4] = {{0.f}};
#pragma unroll 4
  for (int k=0;k<128;k++){
    float4 w = *(const float4*)&Ws[k][tx<<2];
    float wv[4] = {w.x, w.y, w.z, w.w};
    float av[4];
#pragma unroll
    for (int i=0;i<4;i++) av[i] = As[(ty<<2)+i][k];
#pragma unroll
    for (int i=0;i<4;i++)
#pragma unroll
      for (int j=0;j<4;j++) acc[i][j] = fmaf(av[i], wv[j], acc[i][j]);
  }
#pragma unroll
  for (int i=0;i<4;i++){
    int r = row0 + (ty<<2) + i;
    if (r >= NN) continue;
#pragma unroll
    for (int j=0;j<4;j++)
      C[r*HD + col0 + (tx<<2) + j] = acc[i][j];
  }
  const int h = col0 >> 7;
  const int cb = (col0 & 127) + (tx<<2);
  float ps[4], pd[4];
#pragma unroll
  for (int i=0;i<4;i++){
    float s_ = 0.f, d_ = 0.f;
#pragma unroll
    for (int j=0;j<4;j++){
      s_ = fmaf(acc[i][j], att_src[h*D + cb + j], s_);
      d_ = fmaf(acc[i][j], att_dst[h*D + cb + j], d_);
    }
    ps[i] = s_; pd[i] = d_;
  }
#pragma unroll
  for (int o=8;o>0;o>>=1){
#pragma unroll
    for (int i=0;i<4;i++){
      ps[i] += __shfl_xor(ps[i], o);
      pd[i] += __shfl_xor(pd[i], o);
    }
  }
  if (tx == 0){
#pragma unroll
    for (int i=0;i<4;i++){
      int r = row0 + (ty<<2) + i;
      if (r < NN){
        atomicAdd(&a_src[r*4 + h], ps[i]);
        atomicAdd(&a_dst[r*4 + h], pd[i]);
      }
    }
  }
}

// ---------------- GCN gather: XCD-sliced by channel half ----------------
// grid = (NN/16)*8 blocks; sub=blockIdx&7 -> XCDs 0-3 do ch 0-63, 4-7 do 64-127
__global__ __launch_bounds__(256) void k_gcn_agg(const float* __restrict__ xw,
                                                 const float* __restrict__ dinv,
                                                 const int* __restrict__ ioff,
                                                 const int* __restrict__ csr,
                                                 const float* __restrict__ bias,
                                                 float* __restrict__ out){
  __shared__ float2 snm[4][64];
  const int sub  = blockIdx.x & 7;
  const int ch   = sub >> 2;               // channel half
  const int g    = blockIdx.x >> 3;        // 0..624
  const int wv   = threadIdx.x >> 6;
  const int lane = threadIdx.x & 63;
  const int w    = g*16 + (sub & 3)*4 + wv;   // node < NN
  const int c    = ch*64 + lane;
  const int beg = ioff[w], end = ioff[w+1];
  float din = dinv[w];
  float ax = xw[w*D + c] * din;
  for (int jb = beg; jb < end; jb += 64){
    int cnt = end - jb; if (cnt > 64) cnt = 64;
    if (lane < cnt){
      int s = csr[jb + lane];
      snm[wv][lane] = make_float2(dinv[s], __int_as_float(s));
    }
    __builtin_amdgcn_wave_barrier();
#pragma unroll 4
    for (int l=0; l<cnt; l++){
      float2 t = snm[wv][l];
      int ss = __float_as_int(t.y);
      ax = fmaf(t.x, xw[ss*D + c], ax);
    }
    __builtin_amdgcn_wave_barrier();
  }
  out[w*D + c] = fmaxf(fmaf(ax, din, bias[c]), 0.f);
}

// ---------------- GAT gather: XCD-sliced (head-pair x channel-half) -------
// grid = (NN/8)*8; sub=blockIdx&7; slice=sub>>1 in [0,4) = (hp, ch).
// Slice writes its channel-half of partial buffer p{hp}; combine adds them.
__global__ __launch_bounds__(256) void k_gat_agg(const float* __restrict__ hg,
                                                 const float* __restrict__ a_src,
                                                 const float* __restrict__ a_dst,
                                                 const int* __restrict__ ioff,
                                                 const int* __restrict__ csr,
                                                 float* __restrict__ p0,
                                                 float* __restrict__ p1){
  __shared__ float2 sal[4][64];
  __shared__ int    ssr[4][64];
  const int sub   = blockIdx.x & 7;
  const int slice = sub >> 1;              // 0..3
  const int hp    = slice >> 1;            // head pair
  const int ch    = slice & 1;             // channel half
  const int g     = blockIdx.x >> 3;       // 0..1249
  const int wv    = threadIdx.x >> 6;
  const int lane  = threadIdx.x & 63;
  const int w     = g*8 + (sub & 1)*4 + wv;   // node < NN
  const int c     = ch*64 + lane;
  const int h0    = hp*2;
  const int beg = ioff[w], end = ioff[w+1];
  float2 ad  = *(const float2*)&a_dst[w*4 + h0];
  float2 asn = *(const float2*)&a_src[w*4 + h0];
  float e0 = __expf(lrelu(asn.x + ad.x));
  float e1 = __expf(lrelu(asn.y + ad.y));
  float den0 = 0.f, den1 = 0.f;            // self term added once after reduce
  const float* hrow = &hg[(size_t)w*HD + h0*D + c];
  float o0 = e0 * hrow[0];
  float o1 = e1 * hrow[D];

  for (int jb = beg; jb < end; jb += 64){
    int cnt = end - jb; if (cnt > 64) cnt = 64;
    if (lane < cnt){
      int s = csr[jb + lane];
      float2 as = *(const float2*)&a_src[s*4 + h0];
      float g0 = __expf(lrelu(as.x + ad.x));
      float g1 = __expf(lrelu(as.y + ad.y));
      sal[wv][lane] = make_float2(g0, g1);
      ssr[wv][lane] = s;
      den0 += g0; den1 += g1;
    }
    __builtin_amdgcn_wave_barrier();
#pragma unroll 4
    for (int l=0; l<cnt; l++){
      float2 b = sal[wv][l];
      const float* hs = &hg[(size_t)ssr[wv][l]*HD + h0*D + c];
      o0 = fmaf(b.x, hs[0], o0);
      o1 = fmaf(b.y, hs[D], o1);
    }
    __builtin_amdgcn_wave_barrier();
  }
#pragma unroll
  for (int o=32; o>0; o>>=1){
    den0 += __shfl_xor(den0, o);
    den1 += __shfl_xor(den1, o);
  }
  den0 += e0; den1 += e1;
  float res = o0*(0.25f/den0) + o1*(0.25f/den1);
  (hp ? p1 : p0)[w*D + c] = res;
}

// h2 = relu(p0 + p1 + bias)
__global__ __launch_bounds__(256) void k_combine(const float* __restrict__ p0,
                                                 const float* __restrict__ p1,
                                                 const float* __restrict__ bias,
                                                 float* __restrict__ h2){
  int t = blockIdx.x*256 + threadIdx.x;
  if (t >= NN*D) return;
  h2[t] = fmaxf(p0[t] + p1[t] + bias[t & 127], 0.f);
}

// ---------------- Fused MLP + heads ----------------
__global__ __launch_bounds__(256) void k_mlp(const float* __restrict__ h2,
                                             const float* __restrict__ w1,
                                             const float* __restrict__ b1,
                                             const float* __restrict__ w2,
                                             const float* __restrict__ b2,
                                             const float* __restrict__ wmu,
                                             const float* __restrict__ bmu,
                                             const float* __restrict__ wlv,
                                             const float* __restrict__ blv,
                                             float* __restrict__ out){
  __shared__ float hA[64][132];
  __shared__ float hB[64][132];
  __shared__ float Ws[128][68];
  const int tid  = threadIdx.x;
  const int row0 = blockIdx.x*64;
  const int tx = tid & 15, ty = tid >> 4;

#pragma unroll
  for (int i=0;i<8;i++){
    int f  = tid + i*256;
    int r  = f >> 5;
    int k4 = (f & 31) << 2;
    int rr = row0 + r;
    float4 v = make_float4(0.f,0.f,0.f,0.f);
    if (rr < NN) v = *(const float4*)&h2[rr*D + k4];
    *(float4*)&hA[r][k4] = v;
  }

  float (*S)[132] = hA;
  float (*T)[132] = hB;
#pragma unroll
  for (int layer=0; layer<2; layer++){
    const float* W  = layer ? w2 : w1;
    const float* bb = layer ? b2 : b1;
    for (int cc=0; cc<2; cc++){
      __syncthreads();
#pragma unroll
      for (int i=0;i<8;i++){
        int f  = tid + i*256;
        int k  = f >> 4;
        int c4 = (f & 15) << 2;
        *(float4*)&Ws[k][c4] = *(const float4*)&W[k*D + cc*64 + c4];
      }
      __syncthreads();
      float acc[4][4] = {{0.f}};
#pragma unroll 4
      for (int k=0;k<128;k++){
        float4 wvv = *(const float4*)&Ws[k][tx<<2];
        float wv[4] = {wvv.x, wvv.y, wvv.z, wvv.w};
        float av[4];
#pragma unroll
        for (int i=0;i<4;i++) av[i] = S[(ty<<2)+i][k];
#pragma unroll
        for (int i=0;i<4;i++)
#pragma unroll
          for (int j=0;j<4;j++) acc[i][j] = fmaf(av[i], wv[j], acc[i][j]);
      }
#pragma unroll
      for (int i=0;i<4;i++)
#pragma unroll
        for (int j=0;j<4;j++){
          int col = cc*64 + (tx<<2) + j;
          T[(ty<<2)+i][col] = fmaxf(acc[i][j] + bb[col], 0.f);
        }
    }
    float (*tmp)[132] = S; S = T; T = tmp;
  }
  for (int cc=0; cc<2; cc++){
    const float* W  = cc ? wlv : wmu;
    const float* bb = cc ? blv : bmu;
    float* ob = out + (size_t)cc*NN*ZD;
    __syncthreads();
#pragma unroll
    for (int i=0;i<8;i++){
      int f  = tid + i*256;
      int k  = f >> 4;
      int c4 = (f & 15) << 2;
      *(float4*)&Ws[k][c4] = *(const float4*)&W[k*ZD + c4];
    }
    __syncthreads();
    float acc[4][4] = {{0.f}};
#pragma unroll 4
    for (int k=0;k<128;k++){
      float4 wvv = *(const float4*)&Ws[k][tx<<2];
      float wv[4] = {wvv.x, wvv.y, wvv.z, wvv.w};
      float av[4];
#pragma unroll
      for (int i=0;i<4;i++) av[i] = S[(ty<<2)+i][k];
#pragma unroll
      for (int i=0;i<4;i++)
#pragma unroll
        for (int j=0;j<4;j++) acc[i][j] = fmaf(av[i], wv[j], acc[i][j]);
    }
#pragma unroll
    for (int i=0;i<4;i++){
      int r = row0 + (ty<<2) + i;
      if (r >= NN) continue;
      float4 v = make_float4(acc[i][0] + bb[(tx<<2)+0],
                             acc[i][1] + bb[(tx<<2)+1],
                             acc[i][2] + bb[(tx<<2)+2],
                             acc[i][3] + bb[(tx<<2)+3]);
      *(float4*)&ob[r*ZD + (tx<<2)] = v;
    }
  }
}

extern "C" void kernel_launch(void* const* d_in, const int* in_sizes, int n_in,
                              void* d_out, int out_size, void* d_ws, size_t ws_size,
                              hipStream_t stream){
  const float* x     = (const float*)d_in[0];
  const int*   ei    = (const int*)d_in[1];
  const float* gcn_w = (const float*)d_in[2];
  const float* gcn_b = (const float*)d_in[3];
  const float* gat_w = (const float*)d_in[4];
  const float* att_s = (const float*)d_in[5];
  const float* att_d = (const float*)d_in[6];
  const float* gat_b = (const float*)d_in[7];
  const float* w1    = (const float*)d_in[8];
  const float* b1    = (const float*)d_in[9];
  const float* w2    = (const float*)d_in[10];
  const float* b2    = (const float*)d_in[11];
  const float* mu_w  = (const float*)d_in[12];
  const float* mu_b  = (const float*)d_in[13];
  const float* lv_w  = (const float*)d_in[14];
  const float* lv_b  = (const float*)d_in[15];
  const int E = in_sizes[1] / 2;
  const int* src = ei;
  const int* dst = ei + E;

  float* ws    = (float*)d_ws;
  float* xw    = ws;                 // N*128 (GCN proj; later GAT partial p0)
  float* h1    = xw + NN*D;          // N*128 (GCN out; later GAT partial p1)
  float* h2    = h1 + NN*D;          // N*128
  float* hg    = h2 + NN*D;          // N*512
  float* dinv  = hg + NN*HD;         // N
  float* a_src = dinv + NN;          // N*4
  float* a_dst = a_src + NN*NH;      // N*4 (contiguous with a_src)
  int*   ioff  = (int*)(a_dst + NN*NH);  // N+1
  int*   icur  = ioff + NN + 1;          // N
  int*   csr   = icur + NN;              // E

  const int gN = (NN + 255)/256;
  const int gE = (E + 255)/256;
  const int gR = (NN + 63)/64;
  const int gND = (NN*D + 255)/256;

  // CSR build (+ zero a_src/a_dst for the gemm_att epilogue atomics)
  k_zero_int<<<gN, 256, 0, stream>>>(icur, NN);
  k_hist<<<gE, 256, 0, stream>>>(dst, icur, E);
  k_scan<<<1, 1024, 0, stream>>>(icur, ioff, dinv);
  k_fill<<<gE, 256, 0, stream>>>(src, dst, icur, csr, E, a_src);

  // GCN
  k_gemm<<<dim3(gR,2), 256, 0, stream>>>(x, gcn_w, D, nullptr, xw, D, NN, 0);
  k_gcn_agg<<<(NN/16)*8, 256, 0, stream>>>(xw, dinv, ioff, csr, gcn_b, h1);

  // GAT (projection + fused attention coefficients)
  k_gemm_att<<<dim3(gR,8), 256, 0, stream>>>(h1, gat_w, hg, att_s, att_d,
                                             a_src, a_dst);
  // XCD-sliced gather -> partials in xw (hp0) and h1 (hp1), then combine
  k_gat_agg<<<(NN/8)*8, 256, 0, stream>>>(hg, a_src, a_dst, ioff, csr, xw, h1);
  k_combine<<<gND, 256, 0, stream>>>(xw, h1, gat_b, h2);

  // MLP + heads fused
  k_mlp<<<gR, 256, 0, stream>>>(h2, w1, b1, w2, b2, mu_w, mu_b, lv_w, lv_b,
                                (float*)d_out);
}

// Round 8
// 199.318 us; speedup vs baseline: 6.3836x; 1.0458x over previous
//
#include <hip/hip_runtime.h>

#define NN 10000
#define D 128
#define NH 4
#define HD 512   // NH * D
#define ZD 64

__device__ __forceinline__ float lrelu(float x){ return x > 0.0f ? x : 0.2f*x; }

// ---------------- CSR build ----------------
__global__ __launch_bounds__(256) void k_zero_int(int* __restrict__ a, int n){
  int i = blockIdx.x*256 + threadIdx.x;
  if (i < n) a[i] = 0;
}

__global__ __launch_bounds__(256) void k_hist(const int* __restrict__ dst,
                                              int* __restrict__ deg, int E){
  int i = blockIdx.x*256 + threadIdx.x;
  if (i < E) atomicAdd(&deg[dst[i]], 1);
}

// single block of 1024: exclusive scan of deg -> ioff, cursor reset, dinv
__global__ __launch_bounds__(1024) void k_scan(int* __restrict__ deg,
                                               int* __restrict__ ioff,
                                               float* __restrict__ dinv){
  __shared__ int part[1024];
  const int tid = threadIdx.x;
  const int base = tid*10;
  int local[10]; int s = 0;
#pragma unroll
  for (int i=0;i<10;i++){
    int idx = base+i;
    int v = (idx < NN) ? deg[idx] : 0;
    if (idx < NN) dinv[idx] = rsqrtf(1.0f + (float)v);
    local[i] = s; s += v;
  }
  part[tid] = s;
  __syncthreads();
  for (int o=1;o<1024;o<<=1){
    int v = (tid>=o) ? part[tid-o] : 0;
    __syncthreads();
    part[tid] += v;
    __syncthreads();
  }
  int excl = part[tid] - s;
#pragma unroll
  for (int i=0;i<10;i++){
    int idx = base+i;
    if (idx < NN){
      int o = excl + local[i];
      ioff[idx] = o;
      deg[idx]  = o;    // cursor reset
    }
  }
  if (tid == 1023) ioff[NN] = part[1023];
}

__global__ __launch_bounds__(256) void k_fill(const int* __restrict__ src,
                                              const int* __restrict__ dst,
                                              int* __restrict__ cur,
                                              int* __restrict__ csr, int E){
  int i = blockIdx.x*256 + threadIdx.x;
  if (i >= E) return;
  int pos = atomicAdd(&cur[dst[i]], 1);
  csr[pos] = src[i];
}

// ---------------- generic GEMM (GCN projection) ----------------
__global__ __launch_bounds__(256) void k_gemm(const float* __restrict__ A,
                                              const float* __restrict__ W, int ldw,
                                              const float* __restrict__ bias,
                                              float* __restrict__ C, int ldc,
                                              int nrows, int do_relu){
  __shared__ float As[64][132];
  __shared__ float Ws[128][68];
  const int tid  = threadIdx.x;
  const int row0 = blockIdx.x*64;
  const int col0 = blockIdx.y*64;
#pragma unroll
  for (int i=0;i<8;i++){
    int f  = tid + i*256;
    int r  = f >> 5;
    int k4 = (f & 31) << 2;
    int rr = row0 + r;
    float4 v = make_float4(0.f,0.f,0.f,0.f);
    if (rr < nrows) v = *(const float4*)&A[rr*D + k4];
    *(float4*)&As[r][k4] = v;
  }
#pragma unroll
  for (int i=0;i<8;i++){
    int f  = tid + i*256;
    int k  = f >> 4;
    int c4 = (f & 15) << 2;
    float4 v = *(const float4*)&W[k*ldw + col0 + c4];
    *(float4*)&Ws[k][c4] = v;
  }
  __syncthreads();
  const int tx = tid & 15, ty = tid >> 4;
  float acc[4][4] = {{0.f}};
#pragma unroll 4
  for (int k=0;k<128;k++){
    float4 w = *(const float4*)&Ws[k][tx<<2];
    float wv[4] = {w.x, w.y, w.z, w.w};
    float av[4];
#pragma unroll
    for (int i=0;i<4;i++) av[i] = As[(ty<<2)+i][k];
#pragma unroll
    for (int i=0;i<4;i++)
#pragma unroll
      for (int j=0;j<4;j++) acc[i][j] = fmaf(av[i], wv[j], acc[i][j]);
  }
#pragma unroll
  for (int i=0;i<4;i++){
    int r = row0 + (ty<<2) + i;
    if (r >= nrows) continue;
#pragma unroll
    for (int j=0;j<4;j++){
      int c = col0 + (tx<<2) + j;
      float v = acc[i][j];
      if (bias) v += bias[c];
      if (do_relu) v = fmaxf(v, 0.f);
      C[r*ldc + c] = v;
    }
  }
}

// ---------------- GCN gather: XCD-sliced by channel half ----------------
__global__ __launch_bounds__(256) void k_gcn_agg(const float* __restrict__ xw,
                                                 const float* __restrict__ dinv,
                                                 const int* __restrict__ ioff,
                                                 const int* __restrict__ csr,
                                                 const float* __restrict__ bias,
                                                 float* __restrict__ out){
  __shared__ float2 snm[4][64];
  const int sub  = blockIdx.x & 7;
  const int ch   = sub >> 2;               // channel half
  const int g    = blockIdx.x >> 3;        // 0..624
  const int wv   = threadIdx.x >> 6;
  const int lane = threadIdx.x & 63;
  const int w    = g*16 + (sub & 3)*4 + wv;   // node < NN
  const int c    = ch*64 + lane;
  const int beg = ioff[w], end = ioff[w+1];
  float din = dinv[w];
  float ax = xw[w*D + c] * din;
  for (int jb = beg; jb < end; jb += 64){
    int cnt = end - jb; if (cnt > 64) cnt = 64;
    if (lane < cnt){
      int s = csr[jb + lane];
      snm[wv][lane] = make_float2(dinv[s], __int_as_float(s));
    }
    __builtin_amdgcn_wave_barrier();
#pragma unroll 4
    for (int l=0; l<cnt; l++){
      float2 t = snm[wv][l];
      int ss = __float_as_int(t.y);
      ax = fmaf(t.x, xw[ss*D + c], ax);
    }
    __builtin_amdgcn_wave_barrier();
  }
  out[w*D + c] = fmaxf(fmaf(ax, din, bias[c]), 0.f);
}

// ---------------- projected attention vectors ----------------
// w_as[h][k] = sum_c gat_w[k, h*128+c] * att_src[h,c]   (w_ad likewise)
__global__ __launch_bounds__(128) void k_watt(const float* __restrict__ gat_w,
                                              const float* __restrict__ att_src,
                                              const float* __restrict__ att_dst,
                                              float* __restrict__ w_as,
                                              float* __restrict__ w_ad){
  const int h = blockIdx.x;
  const int k = threadIdx.x;
  const float* wrow = &gat_w[k*HD + h*D];
  const float* as   = &att_src[h*D];
  const float* ad   = &att_dst[h*D];
  float s = 0.f, d = 0.f;
#pragma unroll 4
  for (int c=0;c<D;c++){
    float wv = wrow[c];
    s = fmaf(wv, as[c], s);
    d = fmaf(wv, ad[c], d);
  }
  w_as[h*D + k] = s;
  w_ad[h*D + k] = d;
}

// ---------------- attention logits: a_src/a_dst = h1 @ w_as/w_ad ----------
// block = 256 = 4 waves = 4 nodes; w_as||w_ad contiguous (1024 floats) in LDS
__global__ __launch_bounds__(256) void k_att2(const float* __restrict__ h1,
                                              const float* __restrict__ w_as, // w_ad contiguous after
                                              float* __restrict__ a_src,
                                              float* __restrict__ a_dst){
  __shared__ float sw[8][128];
  const int tid = threadIdx.x;
#pragma unroll
  for (int i=0;i<4;i++) ((float*)sw)[tid + i*256] = w_as[tid + i*256];
  __syncthreads();
  const int wv = tid >> 6, lane = tid & 63;
  const int n = blockIdx.x*4 + wv;           // NN divisible by 4
  float2 v = *(const float2*)&h1[n*D + lane*2];
#pragma unroll
  for (int o=0;o<8;o++){
    float t = v.x*sw[o][lane*2] + v.y*sw[o][lane*2+1];
#pragma unroll
    for (int off=32; off>0; off>>=1) t += __shfl_xor(t, off);
    if (lane == 0){
      if (o < 4) a_src[n*4 + o] = t;
      else       a_dst[n*4 + (o-4)] = t;
    }
  }
}

// ---------------- GAT gather in h1-space: XCD-sliced by channel half ------
// agg[n][h*128+c] = ( e_h*h1[n,c] + sum_s exp(lrelu(as_h+ad_h))*h1[s,c] ) * 0.25/den_h
__global__ __launch_bounds__(256) void k_gat_agg2(const float* __restrict__ h1,
                                                  const float* __restrict__ a_src,
                                                  const float* __restrict__ a_dst,
                                                  const int* __restrict__ ioff,
                                                  const int* __restrict__ csr,
                                                  float* __restrict__ agg){
  __shared__ float4 sal[4][64];
  __shared__ int    ssr[4][64];
  const int sub  = blockIdx.x & 7;
  const int ch   = sub >> 2;               // channel half
  const int g    = blockIdx.x >> 3;        // 0..624
  const int wv   = threadIdx.x >> 6;
  const int lane = threadIdx.x & 63;
  const int w    = g*16 + (sub & 3)*4 + wv;   // node < NN
  const int c    = ch*64 + lane;
  const int beg = ioff[w], end = ioff[w+1];
  float4 ad  = *(const float4*)&a_dst[w*4];
  float4 asn = *(const float4*)&a_src[w*4];
  float e0 = __expf(lrelu(asn.x + ad.x));
  float e1 = __expf(lrelu(asn.y + ad.y));
  float e2 = __expf(lrelu(asn.z + ad.z));
  float e3 = __expf(lrelu(asn.w + ad.w));
  float hv = h1[w*D + c];
  float o0 = e0*hv, o1 = e1*hv, o2 = e2*hv, o3 = e3*hv;
  float den0=0.f, den1=0.f, den2=0.f, den3=0.f;   // self added after reduce

  for (int jb = beg; jb < end; jb += 64){
    int cnt = end - jb; if (cnt > 64) cnt = 64;
    if (lane < cnt){
      int s = csr[jb + lane];
      float4 as = *(const float4*)&a_src[s*4];
      float g0 = __expf(lrelu(as.x + ad.x));
      float g1 = __expf(lrelu(as.y + ad.y));
      float g2 = __expf(lrelu(as.z + ad.z));
      float g3 = __expf(lrelu(as.w + ad.w));
      sal[wv][lane] = make_float4(g0,g1,g2,g3);
      ssr[wv][lane] = s;
      den0 += g0; den1 += g1; den2 += g2; den3 += g3;
    }
    __builtin_amdgcn_wave_barrier();
#pragma unroll 4
    for (int l=0; l<cnt; l++){
      float4 b = sal[wv][l];
      float sv = h1[ssr[wv][l]*D + c];
      o0 = fmaf(b.x, sv, o0);
      o1 = fmaf(b.y, sv, o1);
      o2 = fmaf(b.z, sv, o2);
      o3 = fmaf(b.w, sv, o3);
    }
    __builtin_amdgcn_wave_barrier();
  }
#pragma unroll
  for (int o=32; o>0; o>>=1){
    den0 += __shfl_xor(den0, o);
    den1 += __shfl_xor(den1, o);
    den2 += __shfl_xor(den2, o);
    den3 += __shfl_xor(den3, o);
  }
  den0 += e0; den1 += e1; den2 += e2; den3 += e3;
  float* ab = &agg[(size_t)w*HD + c];
  ab[0*D] = o0 * (0.25f/den0);
  ab[1*D] = o1 * (0.25f/den1);
  ab[2*D] = o2 * (0.25f/den2);
  ab[3*D] = o3 * (0.25f/den3);
}

// ---------------- h2 = relu( sum_h agg[:,h]@gat_w[:,h-block] + gat_b ) ----
__global__ __launch_bounds__(256) void k_gemm2(const float* __restrict__ agg,
                                               const float* __restrict__ W,
                                               const float* __restrict__ bias,
                                               float* __restrict__ h2){
  __shared__ float As[64][132];
  __shared__ float Ws[128][68];
  const int tid  = threadIdx.x;
  const int row0 = blockIdx.x*64;
  const int col0 = blockIdx.y*64;
  const int tx = tid & 15, ty = tid >> 4;
  float acc[4][4] = {{0.f}};
  for (int h=0; h<NH; h++){
    __syncthreads();
#pragma unroll
    for (int i=0;i<8;i++){
      int f  = tid + i*256;
      int r  = f >> 5;
      int k4 = (f & 31) << 2;
      int rr = row0 + r;
      float4 v = make_float4(0.f,0.f,0.f,0.f);
      if (rr < NN) v = *(const float4*)&agg[(size_t)rr*HD + h*D + k4];
      *(float4*)&As[r][k4] = v;
    }
#pragma unroll
    for (int i=0;i<8;i++){
      int f  = tid + i*256;
      int k  = f >> 4;
      int c4 = (f & 15) << 2;
      *(float4*)&Ws[k][c4] = *(const float4*)&W[k*HD + h*D + col0 + c4];
    }
    __syncthreads();
#pragma unroll 4
    for (int k=0;k<128;k++){
      float4 w = *(const float4*)&Ws[k][tx<<2];
      float wv[4] = {w.x, w.y, w.z, w.w};
      float av[4];
#pragma unroll
      for (int i=0;i<4;i++) av[i] = As[(ty<<2)+i][k];
#pragma unroll
      for (int i=0;i<4;i++)
#pragma unroll
        for (int j=0;j<4;j++) acc[i][j] = fmaf(av[i], wv[j], acc[i][j]);
    }
  }
#pragma unroll
  for (int i=0;i<4;i++){
    int r = row0 + (ty<<2) + i;
    if (r >= NN) continue;
#pragma unroll
    for (int j=0;j<4;j++){
      int col = col0 + (tx<<2) + j;
      h2[r*D + col] = fmaxf(acc[i][j] + bias[col], 0.f);
    }
  }
}

// ---------------- Fused MLP + heads ----------------
__global__ __launch_bounds__(256) void k_mlp(const float* __restrict__ h2,
                                             const float* __restrict__ w1,
                                             const float* __restrict__ b1,
                                             const float* __restrict__ w2,
                                             const float* __restrict__ b2,
                                             const float* __restrict__ wmu,
                                             const float* __restrict__ bmu,
                                             const float* __restrict__ wlv,
                                             const float* __restrict__ blv,
                                             float* __restrict__ out){
  __shared__ float hA[64][132];
  __shared__ float hB[64][132];
  __shared__ float Ws[128][68];
  const int tid  = threadIdx.x;
  const int row0 = blockIdx.x*64;
  const int tx = tid & 15, ty = tid >> 4;

#pragma unroll
  for (int i=0;i<8;i++){
    int f  = tid + i*256;
    int r  = f >> 5;
    int k4 = (f & 31) << 2;
    int rr = row0 + r;
    float4 v = make_float4(0.f,0.f,0.f,0.f);
    if (rr < NN) v = *(const float4*)&h2[rr*D + k4];
    *(float4*)&hA[r][k4] = v;
  }

  float (*S)[132] = hA;
  float (*T)[132] = hB;
#pragma unroll
  for (int layer=0; layer<2; layer++){
    const float* W  = layer ? w2 : w1;
    const float* bb = layer ? b2 : b1;
    for (int cc=0; cc<2; cc++){
      __syncthreads();
#pragma unroll
      for (int i=0;i<8;i++){
        int f  = tid + i*256;
        int k  = f >> 4;
        int c4 = (f & 15) << 2;
        *(float4*)&Ws[k][c4] = *(const float4*)&W[k*D + cc*64 + c4];
      }
      __syncthreads();
      float acc[4][4] = {{0.f}};
#pragma unroll 4
      for (int k=0;k<128;k++){
        float4 wvv = *(const float4*)&Ws[k][tx<<2];
        float wv[4] = {wvv.x, wvv.y, wvv.z, wvv.w};
        float av[4];
#pragma unroll
        for (int i=0;i<4;i++) av[i] = S[(ty<<2)+i][k];
#pragma unroll
        for (int i=0;i<4;i++)
#pragma unroll
          for (int j=0;j<4;j++) acc[i][j] = fmaf(av[i], wv[j], acc[i][j]);
      }
#pragma unroll
      for (int i=0;i<4;i++)
#pragma unroll
        for (int j=0;j<4;j++){
          int col = cc*64 + (tx<<2) + j;
          T[(ty<<2)+i][col] = fmaxf(acc[i][j] + bb[col], 0.f);
        }
    }
    float (*tmp)[132] = S; S = T; T = tmp;
  }
  for (int cc=0; cc<2; cc++){
    const float* W  = cc ? wlv : wmu;
    const float* bb = cc ? blv : bmu;
    float* ob = out + (size_t)cc*NN*ZD;
    __syncthreads();
#pragma unroll
    for (int i=0;i<8;i++){
      int f  = tid + i*256;
      int k  = f >> 4;
      int c4 = (f & 15) << 2;
      *(float4*)&Ws[k][c4] = *(const float4*)&W[k*ZD + c4];
    }
    __syncthreads();
    float acc[4][4] = {{0.f}};
#pragma unroll 4
    for (int k=0;k<128;k++){
      float4 wvv = *(const float4*)&Ws[k][tx<<2];
      float wv[4] = {wvv.x, wvv.y, wvv.z, wvv.w};
      float av[4];
#pragma unroll
      for (int i=0;i<4;i++) av[i] = S[(ty<<2)+i][k];
#pragma unroll
      for (int i=0;i<4;i++)
#pragma unroll
        for (int j=0;j<4;j++) acc[i][j] = fmaf(av[i], wv[j], acc[i][j]);
    }
#pragma unroll
    for (int i=0;i<4;i++){
      int r = row0 + (ty<<2) + i;
      if (r >= NN) continue;
      float4 v = make_float4(acc[i][0] + bb[(tx<<2)+0],
                             acc[i][1] + bb[(tx<<2)+1],
                             acc[i][2] + bb[(tx<<2)+2],
                             acc[i][3] + bb[(tx<<2)+3]);
      *(float4*)&ob[r*ZD + (tx<<2)] = v;
    }
  }
}

extern "C" void kernel_launch(void* const* d_in, const int* in_sizes, int n_in,
                              void* d_out, int out_size, void* d_ws, size_t ws_size,
                              hipStream_t stream){
  const float* x     = (const float*)d_in[0];
  const int*   ei    = (const int*)d_in[1];
  const float* gcn_w = (const float*)d_in[2];
  const float* gcn_b = (const float*)d_in[3];
  const float* gat_w = (const float*)d_in[4];
  const float* att_s = (const float*)d_in[5];
  const float* att_d = (const float*)d_in[6];
  const float* gat_b = (const float*)d_in[7];
  const float* w1    = (const float*)d_in[8];
  const float* b1    = (const float*)d_in[9];
  const float* w2    = (const float*)d_in[10];
  const float* b2    = (const float*)d_in[11];
  const float* mu_w  = (const float*)d_in[12];
  const float* mu_b  = (const float*)d_in[13];
  const float* lv_w  = (const float*)d_in[14];
  const float* lv_b  = (const float*)d_in[15];
  const int E = in_sizes[1] / 2;
  const int* src = ei;
  const int* dst = ei + E;

  float* ws    = (float*)d_ws;
  float* xw    = ws;                 // N*128 (GCN projection)
  float* h1    = xw + NN*D;          // N*128 (GCN output)
  float* h2    = h1 + NN*D;          // N*128 (GAT output)
  float* agg   = h2 + NN*D;          // N*512 (per-head h1-space aggregates)
  float* dinv  = agg + (size_t)NN*HD;// N
  float* w_as  = dinv + NN;          // 512  (w_ad must follow contiguously)
  float* w_ad  = w_as + HD;          // 512
  float* a_src = w_ad + HD;          // N*4
  float* a_dst = a_src + NN*NH;      // N*4
  int*   ioff  = (int*)(a_dst + NN*NH);  // N+1
  int*   icur  = ioff + NN + 1;          // N
  int*   csr   = icur + NN;              // E

  const int gN = (NN + 255)/256;
  const int gE = (E + 255)/256;
  const int gR = (NN + 63)/64;

  // CSR build
  k_zero_int<<<gN, 256, 0, stream>>>(icur, NN);
  k_hist<<<gE, 256, 0, stream>>>(dst, icur, E);
  k_scan<<<1, 1024, 0, stream>>>(icur, ioff, dinv);
  k_fill<<<gE, 256, 0, stream>>>(src, dst, icur, csr, E);

  // projected attention vectors (independent of graph work)
  k_watt<<<NH, 128, 0, stream>>>(gat_w, att_s, att_d, w_as, w_ad);

  // GCN
  k_gemm<<<dim3(gR,2), 256, 0, stream>>>(x, gcn_w, D, nullptr, xw, D, NN, 0);
  k_gcn_agg<<<(NN/16)*8, 256, 0, stream>>>(xw, dinv, ioff, csr, gcn_b, h1);

  // GAT in h1-space
  k_att2<<<NN/4, 256, 0, stream>>>(h1, w_as, a_src, a_dst);
  k_gat_agg2<<<(NN/16)*8, 256, 0, stream>>>(h1, a_src, a_dst, ioff, csr, agg);
  k_gemm2<<<dim3(gR,2), 256, 0, stream>>>(agg, gat_w, gat_b, h2);

  // MLP + heads fused
  k_mlp<<<gR, 256, 0, stream>>>(h2, w1, b1, w2, b2, mu_w, mu_b, lv_w, lv_b,
                                (float*)d_out);
}

// Round 9
// 191.735 us; speedup vs baseline: 6.6360x; 1.0395x over previous
//
#include <hip/hip_runtime.h>

#define NN 10000
#define D 128
#define NH 4
#define HD 512   // NH * D
#define ZD 64

__device__ __forceinline__ float lrelu(float x){ return x > 0.0f ? x : 0.2f*x; }

// ---------------- CSR build ----------------
__global__ __launch_bounds__(256) void k_zero_int(int* __restrict__ a, int n){
  int i = blockIdx.x*256 + threadIdx.x;
  if (i < n) a[i] = 0;
}

__global__ __launch_bounds__(256) void k_hist(const int* __restrict__ dst,
                                              int* __restrict__ deg, int E){
  int i = blockIdx.x*256 + threadIdx.x;
  if (i < E) atomicAdd(&deg[dst[i]], 1);
}

// single block of 1024: exclusive scan of deg -> ioff, cursor reset, dinv
__global__ __launch_bounds__(1024) void k_scan(int* __restrict__ deg,
                                               int* __restrict__ ioff,
                                               float* __restrict__ dinv){
  __shared__ int part[1024];
  const int tid = threadIdx.x;
  const int base = tid*10;
  int local[10]; int s = 0;
#pragma unroll
  for (int i=0;i<10;i++){
    int idx = base+i;
    int v = (idx < NN) ? deg[idx] : 0;
    if (idx < NN) dinv[idx] = rsqrtf(1.0f + (float)v);
    local[i] = s; s += v;
  }
  part[tid] = s;
  __syncthreads();
  for (int o=1;o<1024;o<<=1){
    int v = (tid>=o) ? part[tid-o] : 0;
    __syncthreads();
    part[tid] += v;
    __syncthreads();
  }
  int excl = part[tid] - s;
#pragma unroll
  for (int i=0;i<10;i++){
    int idx = base+i;
    if (idx < NN){
      int o = excl + local[i];
      ioff[idx] = o;
      deg[idx]  = o;    // cursor reset
    }
  }
  if (tid == 1023) ioff[NN] = part[1023];
}

// fill CSR; also zero a_src/a_dst (contiguous, NN*NH*2 floats)
__global__ __launch_bounds__(256) void k_fill(const int* __restrict__ src,
                                              const int* __restrict__ dst,
                                              int* __restrict__ cur,
                                              int* __restrict__ csr, int E,
                                              float* __restrict__ az){
  int i = blockIdx.x*256 + threadIdx.x;
  if (i < NN*NH*2) az[i] = 0.f;
  if (i >= E) return;
  int pos = atomicAdd(&cur[dst[i]], 1);
  csr[pos] = src[i];
}

// ---------------- generic GEMM (GCN projection) ----------------
__global__ __launch_bounds__(256) void k_gemm(const float* __restrict__ A,
                                              const float* __restrict__ W, int ldw,
                                              const float* __restrict__ bias,
                                              float* __restrict__ C, int ldc,
                                              int nrows, int do_relu){
  __shared__ float As[64][132];
  __shared__ float Ws[128][68];
  const int tid  = threadIdx.x;
  const int row0 = blockIdx.x*64;
  const int col0 = blockIdx.y*64;
#pragma unroll
  for (int i=0;i<8;i++){
    int f  = tid + i*256;
    int r  = f >> 5;
    int k4 = (f & 31) << 2;
    int rr = row0 + r;
    float4 v = make_float4(0.f,0.f,0.f,0.f);
    if (rr < nrows) v = *(const float4*)&A[rr*D + k4];
    *(float4*)&As[r][k4] = v;
  }
#pragma unroll
  for (int i=0;i<8;i++){
    int f  = tid + i*256;
    int k  = f >> 4;
    int c4 = (f & 15) << 2;
    float4 v = *(const float4*)&W[k*ldw + col0 + c4];
    *(float4*)&Ws[k][c4] = v;
  }
  __syncthreads();
  const int tx = tid & 15, ty = tid >> 4;
  float acc[4][4] = {{0.f}};
#pragma unroll 4
  for (int k=0;k<128;k++){
    float4 w = *(const float4*)&Ws[k][tx<<2];
    float wv[4] = {w.x, w.y, w.z, w.w};
    float av[4];
#pragma unroll
    for (int i=0;i<4;i++) av[i] = As[(ty<<2)+i][k];
#pragma unroll
    for (int i=0;i<4;i++)
#pragma unroll
      for (int j=0;j<4;j++) acc[i][j] = fmaf(av[i], wv[j], acc[i][j]);
  }
#pragma unroll
  for (int i=0;i<4;i++){
    int r = row0 + (ty<<2) + i;
    if (r >= nrows) continue;
#pragma unroll
    for (int j=0;j<4;j++){
      int c = col0 + (tx<<2) + j;
      float v = acc[i][j];
      if (bias) v += bias[c];
      if (do_relu) v = fmaxf(v, 0.f);
      C[r*ldc + c] = v;
    }
  }
}

// ---------------- projected attention vectors ----------------
__global__ __launch_bounds__(128) void k_watt(const float* __restrict__ gat_w,
                                              const float* __restrict__ att_src,
                                              const float* __restrict__ att_dst,
                                              float* __restrict__ w_as,
                                              float* __restrict__ w_ad){
  const int h = blockIdx.x;
  const int k = threadIdx.x;
  const float* wrow = &gat_w[k*HD + h*D];
  const float* as   = &att_src[h*D];
  const float* ad   = &att_dst[h*D];
  float s = 0.f, d = 0.f;
#pragma unroll 4
  for (int c=0;c<D;c++){
    float wv = wrow[c];
    s = fmaf(wv, as[c], s);
    d = fmaf(wv, ad[c], d);
  }
  w_as[h*D + k] = s;
  w_ad[h*D + k] = d;
}

// ---------------- GCN gather (XCD-sliced by channel half)
//                  + fused attention-logit partial dots ----------------
__global__ __launch_bounds__(256) void k_gcn_agg(const float* __restrict__ xw,
                                                 const float* __restrict__ dinv,
                                                 const int* __restrict__ ioff,
                                                 const int* __restrict__ csr,
                                                 const float* __restrict__ bias,
                                                 const float* __restrict__ w_as,
                                                 const float* __restrict__ w_ad,
                                                 float* __restrict__ out,
                                                 float* __restrict__ a_src,
                                                 float* __restrict__ a_dst){
  __shared__ float2 snm[4][64];
  const int sub  = blockIdx.x & 7;
  const int ch   = sub >> 2;               // channel half
  const int g    = blockIdx.x >> 3;        // 0..624
  const int wv   = threadIdx.x >> 6;
  const int lane = threadIdx.x & 63;
  const int w    = g*16 + (sub & 3)*4 + wv;   // node < NN
  const int c    = ch*64 + lane;
  const int beg = ioff[w], end = ioff[w+1];
  float din = dinv[w];
  float ax = xw[w*D + c] * din;
  for (int jb = beg; jb < end; jb += 64){
    int cnt = end - jb; if (cnt > 64) cnt = 64;
    if (lane < cnt){
      int s = csr[jb + lane];
      snm[wv][lane] = make_float2(dinv[s], __int_as_float(s));
    }
    __builtin_amdgcn_wave_barrier();
#pragma unroll 4
    for (int l=0; l<cnt; l++){
      float2 t = snm[wv][l];
      int ss = __float_as_int(t.y);
      ax = fmaf(t.x, xw[ss*D + c], ax);
    }
    __builtin_amdgcn_wave_barrier();
  }
  float val = fmaxf(fmaf(ax, din, bias[c]), 0.f);
  out[w*D + c] = val;
  // fused attention-logit partials: a_src[w,h] += sum_c val*w_as[h,c]
  float ps[NH], pd[NH];
#pragma unroll
  for (int h=0;h<NH;h++){
    ps[h] = val * w_as[h*D + c];
    pd[h] = val * w_ad[h*D + c];
  }
#pragma unroll
  for (int o=32;o>0;o>>=1){
#pragma unroll
    for (int h=0;h<NH;h++){
      ps[h] += __shfl_xor(ps[h], o);
      pd[h] += __shfl_xor(pd[h], o);
    }
  }
  if (lane == 0){
#pragma unroll
    for (int h=0;h<NH;h++){
      atomicAdd(&a_src[w*4 + h], ps[h]);
      atomicAdd(&a_dst[w*4 + h], pd[h]);
    }
  }
}

// ---------------- GAT gather in h1-space: XCD-sliced by channel half ------
__global__ __launch_bounds__(256) void k_gat_agg2(const float* __restrict__ h1,
                                                  const float* __restrict__ a_src,
                                                  const float* __restrict__ a_dst,
                                                  const int* __restrict__ ioff,
                                                  const int* __restrict__ csr,
                                                  float* __restrict__ agg){
  __shared__ float4 sal[4][64];
  __shared__ int    ssr[4][64];
  const int sub  = blockIdx.x & 7;
  const int ch   = sub >> 2;               // channel half
  const int g    = blockIdx.x >> 3;        // 0..624
  const int wv   = threadIdx.x >> 6;
  const int lane = threadIdx.x & 63;
  const int w    = g*16 + (sub & 3)*4 + wv;   // node < NN
  const int c    = ch*64 + lane;
  const int beg = ioff[w], end = ioff[w+1];
  float4 ad  = *(const float4*)&a_dst[w*4];
  float4 asn = *(const float4*)&a_src[w*4];
  float e0 = __expf(lrelu(asn.x + ad.x));
  float e1 = __expf(lrelu(asn.y + ad.y));
  float e2 = __expf(lrelu(asn.z + ad.z));
  float e3 = __expf(lrelu(asn.w + ad.w));
  float hv = h1[w*D + c];
  float o0 = e0*hv, o1 = e1*hv, o2 = e2*hv, o3 = e3*hv;
  float den0=0.f, den1=0.f, den2=0.f, den3=0.f;   // self added after reduce

  for (int jb = beg; jb < end; jb += 64){
    int cnt = end - jb; if (cnt > 64) cnt = 64;
    if (lane < cnt){
      int s = csr[jb + lane];
      float4 as = *(const float4*)&a_src[s*4];
      float g0 = __expf(lrelu(as.x + ad.x));
      float g1 = __expf(lrelu(as.y + ad.y));
      float g2 = __expf(lrelu(as.z + ad.z));
      float g3 = __expf(lrelu(as.w + ad.w));
      sal[wv][lane] = make_float4(g0,g1,g2,g3);
      ssr[wv][lane] = s;
      den0 += g0; den1 += g1; den2 += g2; den3 += g3;
    }
    __builtin_amdgcn_wave_barrier();
#pragma unroll 4
    for (int l=0; l<cnt; l++){
      float4 b = sal[wv][l];
      float sv = h1[ssr[wv][l]*D + c];
      o0 = fmaf(b.x, sv, o0);
      o1 = fmaf(b.y, sv, o1);
      o2 = fmaf(b.z, sv, o2);
      o3 = fmaf(b.w, sv, o3);
    }
    __builtin_amdgcn_wave_barrier();
  }
#pragma unroll
  for (int o=32; o>0; o>>=1){
    den0 += __shfl_xor(den0, o);
    den1 += __shfl_xor(den1, o);
    den2 += __shfl_xor(den2, o);
    den3 += __shfl_xor(den3, o);
  }
  den0 += e0; den1 += e1; den2 += e2; den3 += e3;
  float* ab = &agg[(size_t)w*HD + c];
  ab[0*D] = o0 * (0.25f/den0);
  ab[1*D] = o1 * (0.25f/den1);
  ab[2*D] = o2 * (0.25f/den2);
  ab[3*D] = o3 * (0.25f/den3);
}

// ---------------- h2 = relu( sum_h agg[:,h]@gat_w[:,h-block] + gat_b ) ----
__global__ __launch_bounds__(256) void k_gemm2(const float* __restrict__ agg,
                                               const float* __restrict__ W,
                                               const float* __restrict__ bias,
                                               float* __restrict__ h2){
  __shared__ float As[64][132];
  __shared__ float Ws[128][68];
  const int tid  = threadIdx.x;
  const int row0 = blockIdx.x*64;
  const int col0 = blockIdx.y*64;
  const int tx = tid & 15, ty = tid >> 4;
  float acc[4][4] = {{0.f}};
  for (int h=0; h<NH; h++){
    __syncthreads();
#pragma unroll
    for (int i=0;i<8;i++){
      int f  = tid + i*256;
      int r  = f >> 5;
      int k4 = (f & 31) << 2;
      int rr = row0 + r;
      float4 v = make_float4(0.f,0.f,0.f,0.f);
      if (rr < NN) v = *(const float4*)&agg[(size_t)rr*HD + h*D + k4];
      *(float4*)&As[r][k4] = v;
    }
#pragma unroll
    for (int i=0;i<8;i++){
      int f  = tid + i*256;
      int k  = f >> 4;
      int c4 = (f & 15) << 2;
      *(float4*)&Ws[k][c4] = *(const float4*)&W[k*HD + h*D + col0 + c4];
    }
    __syncthreads();
#pragma unroll 4
    for (int k=0;k<128;k++){
      float4 w = *(const float4*)&Ws[k][tx<<2];
      float wv[4] = {w.x, w.y, w.z, w.w};
      float av[4];
#pragma unroll
      for (int i=0;i<4;i++) av[i] = As[(ty<<2)+i][k];
#pragma unroll
      for (int i=0;i<4;i++)
#pragma unroll
        for (int j=0;j<4;j++) acc[i][j] = fmaf(av[i], wv[j], acc[i][j]);
    }
  }
#pragma unroll
  for (int i=0;i<4;i++){
    int r = row0 + (ty<<2) + i;
    if (r >= NN) continue;
#pragma unroll
    for (int j=0;j<4;j++){
      int col = col0 + (tx<<2) + j;
      h2[r*D + col] = fmaxf(acc[i][j] + bias[col], 0.f);
    }
  }
}

// ---------------- Fused MLP + heads: 32-row tiles for occupancy ----------
// LDS: hA/hB 32x132 (16.9 KB each) + Ws 128x68 (34.8 KB) = 68.6 KB -> 2/CU
__global__ __launch_bounds__(256) void k_mlp(const float* __restrict__ h2,
                                             const float* __restrict__ w1,
                                             const float* __restrict__ b1,
                                             const float* __restrict__ w2,
                                             const float* __restrict__ b2,
                                             const float* __restrict__ wmu,
                                             const float* __restrict__ bmu,
                                             const float* __restrict__ wlv,
                                             const float* __restrict__ blv,
                                             float* __restrict__ out){
  __shared__ float hA[32][132];
  __shared__ float hB[32][132];
  __shared__ float Ws[128][68];
  const int tid  = threadIdx.x;
  const int row0 = blockIdx.x*32;
  const int tx = tid & 15, ty = tid >> 4;   // 16 cols-of-4 x 16 row-pairs

  // load h2 tile (32 rows x 32 float4 = 1024 float4)
#pragma unroll
  for (int i=0;i<4;i++){
    int f  = tid + i*256;
    int r  = f >> 5;
    int k4 = (f & 31) << 2;
    int rr = row0 + r;
    float4 v = make_float4(0.f,0.f,0.f,0.f);
    if (rr < NN) v = *(const float4*)&h2[rr*D + k4];
    *(float4*)&hA[r][k4] = v;
  }

  float (*S)[132] = hA;
  float (*T)[132] = hB;
#pragma unroll
  for (int layer=0; layer<2; layer++){
    const float* W  = layer ? w2 : w1;
    const float* bb = layer ? b2 : b1;
    for (int cc=0; cc<2; cc++){
      __syncthreads();
#pragma unroll
      for (int i=0;i<8;i++){
        int f  = tid + i*256;      // 2048 float4
        int k  = f >> 4;
        int c4 = (f & 15) << 2;
        *(float4*)&Ws[k][c4] = *(const float4*)&W[k*D + cc*64 + c4];
      }
      __syncthreads();
      float acc[2][4] = {{0.f}};
#pragma unroll 4
      for (int k=0;k<128;k++){
        float4 wvv = *(const float4*)&Ws[k][tx<<2];
        float wv[4] = {wvv.x, wvv.y, wvv.z, wvv.w};
        float av[2];
#pragma unroll
        for (int i=0;i<2;i++) av[i] = S[(ty<<1)+i][k];
#pragma unroll
        for (int i=0;i<2;i++)
#pragma unroll
          for (int j=0;j<4;j++) acc[i][j] = fmaf(av[i], wv[j], acc[i][j]);
      }
#pragma unroll
      for (int i=0;i<2;i++)
#pragma unroll
        for (int j=0;j<4;j++){
          int col = cc*64 + (tx<<2) + j;
          T[(ty<<1)+i][col] = fmaxf(acc[i][j] + bb[col], 0.f);
        }
    }
    float (*tmp)[132] = S; S = T; T = tmp;
  }
  // heads: cc=0 -> mu, cc=1 -> lv
  for (int cc=0; cc<2; cc++){
    const float* W  = cc ? wlv : wmu;
    const float* bb = cc ? blv : bmu;
    float* ob = out + (size_t)cc*NN*ZD;
    __syncthreads();
#pragma unroll
    for (int i=0;i<8;i++){
      int f  = tid + i*256;      // 128 rows x 16 float4 = 2048
      int k  = f >> 4;
      int c4 = (f & 15) << 2;
      *(float4*)&Ws[k][c4] = *(const float4*)&W[k*ZD + c4];
    }
    __syncthreads();
    float acc[2][4] = {{0.f}};
#pragma unroll 4
    for (int k=0;k<128;k++){
      float4 wvv = *(const float4*)&Ws[k][tx<<2];
      float wv[4] = {wvv.x, wvv.y, wvv.z, wvv.w};
      float av[2];
#pragma unroll
      for (int i=0;i<2;i++) av[i] = S[(ty<<1)+i][k];
#pragma unroll
      for (int i=0;i<2;i++)
#pragma unroll
        for (int j=0;j<4;j++) acc[i][j] = fmaf(av[i], wv[j], acc[i][j]);
    }
#pragma unroll
    for (int i=0;i<2;i++){
      int r = row0 + (ty<<1) + i;
      if (r >= NN) continue;
      float4 v = make_float4(acc[i][0] + bb[(tx<<2)+0],
                             acc[i][1] + bb[(tx<<2)+1],
                             acc[i][2] + bb[(tx<<2)+2],
                             acc[i][3] + bb[(tx<<2)+3]);
      *(float4*)&ob[r*ZD + (tx<<2)] = v;
    }
  }
}

extern "C" void kernel_launch(void* const* d_in, const int* in_sizes, int n_in,
                              void* d_out, int out_size, void* d_ws, size_t ws_size,
                              hipStream_t stream){
  const float* x     = (const float*)d_in[0];
  const int*   ei    = (const int*)d_in[1];
  const float* gcn_w = (const float*)d_in[2];
  const float* gcn_b = (const float*)d_in[3];
  const float* gat_w = (const float*)d_in[4];
  const float* att_s = (const float*)d_in[5];
  const float* att_d = (const float*)d_in[6];
  const float* gat_b = (const float*)d_in[7];
  const float* w1    = (const float*)d_in[8];
  const float* b1    = (const float*)d_in[9];
  const float* w2    = (const float*)d_in[10];
  const float* b2    = (const float*)d_in[11];
  const float* mu_w  = (const float*)d_in[12];
  const float* mu_b  = (const float*)d_in[13];
  const float* lv_w  = (const float*)d_in[14];
  const float* lv_b  = (const float*)d_in[15];
  const int E = in_sizes[1] / 2;
  const int* src = ei;
  const int* dst = ei + E;

  float* ws    = (float*)d_ws;
  float* xw    = ws;                 // N*128 (GCN projection)
  float* h1    = xw + NN*D;          // N*128 (GCN output)
  float* h2    = h1 + NN*D;          // N*128 (GAT output)
  float* agg   = h2 + NN*D;          // N*512 (per-head h1-space aggregates)
  float* dinv  = agg + (size_t)NN*HD;// N
  float* w_as  = dinv + NN;          // 512
  float* w_ad  = w_as + HD;          // 512
  float* a_src = w_ad + HD;          // N*4
  float* a_dst = a_src + NN*NH;      // N*4 (contiguous with a_src)
  int*   ioff  = (int*)(a_dst + NN*NH);  // N+1
  int*   icur  = ioff + NN + 1;          // N
  int*   csr   = icur + NN;              // E

  const int gN = (NN + 255)/256;
  const int gE = (E + 255)/256;
  const int gR = (NN + 63)/64;
  const int gM = (NN + 31)/32;

  // CSR build (+ zero a_src/a_dst for gcn_agg epilogue atomics)
  k_zero_int<<<gN, 256, 0, stream>>>(icur, NN);
  k_hist<<<gE, 256, 0, stream>>>(dst, icur, E);
  k_scan<<<1, 1024, 0, stream>>>(icur, ioff, dinv);
  k_fill<<<gE, 256, 0, stream>>>(src, dst, icur, csr, E, a_src);

  // projected attention vectors
  k_watt<<<NH, 128, 0, stream>>>(gat_w, att_s, att_d, w_as, w_ad);

  // GCN (+ fused attention logits)
  k_gemm<<<dim3(gR,2), 256, 0, stream>>>(x, gcn_w, D, nullptr, xw, D, NN, 0);
  k_gcn_agg<<<(NN/16)*8, 256, 0, stream>>>(xw, dinv, ioff, csr, gcn_b,
                                           w_as, w_ad, h1, a_src, a_dst);

  // GAT in h1-space
  k_gat_agg2<<<(NN/16)*8, 256, 0, stream>>>(h1, a_src, a_dst, ioff, csr, agg);
  k_gemm2<<<dim3(gR,2), 256, 0, stream>>>(agg, gat_w, gat_b, h2);

  // MLP + heads fused (32-row tiles)
  k_mlp<<<gM, 256, 0, stream>>>(h2, w1, b1, w2, b2, mu_w, mu_b, lv_w, lv_b,
                                (float*)d_out);
}

// Round 10
// 178.145 us; speedup vs baseline: 7.1423x; 1.0763x over previous
//
#include <hip/hip_runtime.h>

#define NN 10000
#define D 128
#define NH 4
#define HD 512   // NH * D
#define ZD 64

__device__ __forceinline__ float lrelu(float x){ return x > 0.0f ? x : 0.2f*x; }

// ---------------- CSR build ----------------
__global__ __launch_bounds__(256) void k_hist(const int* __restrict__ dst,
                                              int* __restrict__ deg, int E){
  int i = blockIdx.x*256 + threadIdx.x;
  if (i < E) atomicAdd(&deg[dst[i]], 1);
}

// single block of 1024: exclusive scan of deg -> ioff, cursor reset, dinv
__global__ __launch_bounds__(1024) void k_scan(int* __restrict__ deg,
                                               int* __restrict__ ioff,
                                               float* __restrict__ dinv){
  __shared__ int part[1024];
  const int tid = threadIdx.x;
  const int base = tid*10;
  int local[10]; int s = 0;
#pragma unroll
  for (int i=0;i<10;i++){
    int idx = base+i;
    int v = (idx < NN) ? deg[idx] : 0;
    if (idx < NN) dinv[idx] = rsqrtf(1.0f + (float)v);
    local[i] = s; s += v;
  }
  part[tid] = s;
  __syncthreads();
  for (int o=1;o<1024;o<<=1){
    int v = (tid>=o) ? part[tid-o] : 0;
    __syncthreads();
    part[tid] += v;
    __syncthreads();
  }
  int excl = part[tid] - s;
#pragma unroll
  for (int i=0;i<10;i++){
    int idx = base+i;
    if (idx < NN){
      int o = excl + local[i];
      ioff[idx] = o;
      deg[idx]  = o;    // cursor reset
    }
  }
  if (tid == 1023) ioff[NN] = part[1023];
}

// fill CSR; also zero a_src/a_dst (contiguous, NN*NH*2 floats)
__global__ __launch_bounds__(256) void k_fill(const int* __restrict__ src,
                                              const int* __restrict__ dst,
                                              int* __restrict__ cur,
                                              int* __restrict__ csr, int E,
                                              float* __restrict__ az){
  int i = blockIdx.x*256 + threadIdx.x;
  if (i < NN*NH*2) az[i] = 0.f;
  if (i >= E) return;
  int pos = atomicAdd(&cur[dst[i]], 1);
  csr[pos] = src[i];
}

// ---------------- mega front kernel: GCN-proj GEMM + watt + icur zero ------
// bx < 314  : xw = x @ gcn_w  (64x64 tiles)
// bx 314-317: w_as/w_ad projected attention vectors (head = bx-314)
// bx >= 318 : zero icur
__global__ __launch_bounds__(256) void k_mega(const float* __restrict__ x,
                                              const float* __restrict__ gcn_w,
                                              float* __restrict__ xw,
                                              const float* __restrict__ gat_w,
                                              const float* __restrict__ att_src,
                                              const float* __restrict__ att_dst,
                                              float* __restrict__ w_as,
                                              float* __restrict__ w_ad,
                                              int* __restrict__ icur){
  __shared__ float As[64][132];
  __shared__ float Ws[128][68];
  const int bx  = blockIdx.x;
  const int tid = threadIdx.x;
  if (bx < 314){
    const int row0 = (bx >> 1)*64;
    const int col0 = (bx & 1)*64;
#pragma unroll
    for (int i=0;i<8;i++){
      int f  = tid + i*256;
      int r  = f >> 5;
      int k4 = (f & 31) << 2;
      int rr = row0 + r;
      float4 v = make_float4(0.f,0.f,0.f,0.f);
      if (rr < NN) v = *(const float4*)&x[rr*D + k4];
      *(float4*)&As[r][k4] = v;
    }
#pragma unroll
    for (int i=0;i<8;i++){
      int f  = tid + i*256;
      int k  = f >> 4;
      int c4 = (f & 15) << 2;
      *(float4*)&Ws[k][c4] = *(const float4*)&gcn_w[k*D + col0 + c4];
    }
    __syncthreads();
    const int tx = tid & 15, ty = tid >> 4;
    float acc[4][4] = {{0.f}};
#pragma unroll 4
    for (int k=0;k<128;k++){
      float4 w = *(const float4*)&Ws[k][tx<<2];
      float wv[4] = {w.x, w.y, w.z, w.w};
      float av[4];
#pragma unroll
      for (int i=0;i<4;i++) av[i] = As[(ty<<2)+i][k];
#pragma unroll
      for (int i=0;i<4;i++)
#pragma unroll
        for (int j=0;j<4;j++) acc[i][j] = fmaf(av[i], wv[j], acc[i][j]);
    }
#pragma unroll
    for (int i=0;i<4;i++){
      int r = row0 + (ty<<2) + i;
      if (r >= NN) continue;
#pragma unroll
      for (int j=0;j<4;j++)
        xw[r*D + col0 + (tx<<2) + j] = acc[i][j];
    }
  } else if (bx < 318){
    const int h = bx - 314;
    const int k = tid;
    if (k < 128){
      const float* wrow = &gat_w[k*HD + h*D];
      const float* as   = &att_src[h*D];
      const float* ad   = &att_dst[h*D];
      float s = 0.f, d = 0.f;
#pragma unroll 4
      for (int c=0;c<D;c++){
        float wv = wrow[c];
        s = fmaf(wv, as[c], s);
        d = fmaf(wv, ad[c], d);
      }
      w_as[h*D + k] = s;
      w_ad[h*D + k] = d;
    }
  } else {
    int i = (bx - 318)*256 + tid;
    if (i < NN) icur[i] = 0;
  }
}

// ---------------- GCN gather (XCD-sliced by channel half)
//                  + fused attention-logit partial dots ----------------
__global__ __launch_bounds__(256) void k_gcn_agg(const float* __restrict__ xw,
                                                 const float* __restrict__ dinv,
                                                 const int* __restrict__ ioff,
                                                 const int* __restrict__ csr,
                                                 const float* __restrict__ bias,
                                                 const float* __restrict__ w_as,
                                                 const float* __restrict__ w_ad,
                                                 float* __restrict__ out,
                                                 float* __restrict__ a_src,
                                                 float* __restrict__ a_dst){
  __shared__ float2 snm[4][64];
  const int sub  = blockIdx.x & 7;
  const int ch   = sub >> 2;               // channel half
  const int g    = blockIdx.x >> 3;        // 0..624
  const int wv   = threadIdx.x >> 6;
  const int lane = threadIdx.x & 63;
  const int w    = g*16 + (sub & 3)*4 + wv;   // node < NN
  const int c    = ch*64 + lane;
  const int beg = ioff[w], end = ioff[w+1];
  float din = dinv[w];
  float ax = xw[w*D + c] * din;
  for (int jb = beg; jb < end; jb += 64){
    int cnt = end - jb; if (cnt > 64) cnt = 64;
    if (lane < cnt){
      int s = csr[jb + lane];
      snm[wv][lane] = make_float2(dinv[s], __int_as_float(s));
    }
    __builtin_amdgcn_wave_barrier();
#pragma unroll 4
    for (int l=0; l<cnt; l++){
      float2 t = snm[wv][l];
      int ss = __float_as_int(t.y);
      ax = fmaf(t.x, xw[ss*D + c], ax);
    }
    __builtin_amdgcn_wave_barrier();
  }
  float val = fmaxf(fmaf(ax, din, bias[c]), 0.f);
  out[w*D + c] = val;
  float ps[NH], pd[NH];
#pragma unroll
  for (int h=0;h<NH;h++){
    ps[h] = val * w_as[h*D + c];
    pd[h] = val * w_ad[h*D + c];
  }
#pragma unroll
  for (int o=32;o>0;o>>=1){
#pragma unroll
    for (int h=0;h<NH;h++){
      ps[h] += __shfl_xor(ps[h], o);
      pd[h] += __shfl_xor(pd[h], o);
    }
  }
  if (lane == 0){
#pragma unroll
    for (int h=0;h<NH;h++){
      atomicAdd(&a_src[w*4 + h], ps[h]);
      atomicAdd(&a_dst[w*4 + h], pd[h]);
    }
  }
}

// ---------------- GAT gather in h1-space: XCD-sliced by channel half ------
__global__ __launch_bounds__(256) void k_gat_agg2(const float* __restrict__ h1,
                                                  const float* __restrict__ a_src,
                                                  const float* __restrict__ a_dst,
                                                  const int* __restrict__ ioff,
                                                  const int* __restrict__ csr,
                                                  float* __restrict__ agg){
  __shared__ float4 sal[4][64];
  __shared__ int    ssr[4][64];
  const int sub  = blockIdx.x & 7;
  const int ch   = sub >> 2;               // channel half
  const int g    = blockIdx.x >> 3;        // 0..624
  const int wv   = threadIdx.x >> 6;
  const int lane = threadIdx.x & 63;
  const int w    = g*16 + (sub & 3)*4 + wv;   // node < NN
  const int c    = ch*64 + lane;
  const int beg = ioff[w], end = ioff[w+1];
  float4 ad  = *(const float4*)&a_dst[w*4];
  float4 asn = *(const float4*)&a_src[w*4];
  float e0 = __expf(lrelu(asn.x + ad.x));
  float e1 = __expf(lrelu(asn.y + ad.y));
  float e2 = __expf(lrelu(asn.z + ad.z));
  float e3 = __expf(lrelu(asn.w + ad.w));
  float hv = h1[w*D + c];
  float o0 = e0*hv, o1 = e1*hv, o2 = e2*hv, o3 = e3*hv;
  float den0=0.f, den1=0.f, den2=0.f, den3=0.f;   // self added after reduce

  for (int jb = beg; jb < end; jb += 64){
    int cnt = end - jb; if (cnt > 64) cnt = 64;
    if (lane < cnt){
      int s = csr[jb + lane];
      float4 as = *(const float4*)&a_src[s*4];
      float g0 = __expf(lrelu(as.x + ad.x));
      float g1 = __expf(lrelu(as.y + ad.y));
      float g2 = __expf(lrelu(as.z + ad.z));
      float g3 = __expf(lrelu(as.w + ad.w));
      sal[wv][lane] = make_float4(g0,g1,g2,g3);
      ssr[wv][lane] = s;
      den0 += g0; den1 += g1; den2 += g2; den3 += g3;
    }
    __builtin_amdgcn_wave_barrier();
#pragma unroll 4
    for (int l=0; l<cnt; l++){
      float4 b = sal[wv][l];
      float sv = h1[ssr[wv][l]*D + c];
      o0 = fmaf(b.x, sv, o0);
      o1 = fmaf(b.y, sv, o1);
      o2 = fmaf(b.z, sv, o2);
      o3 = fmaf(b.w, sv, o3);
    }
    __builtin_amdgcn_wave_barrier();
  }
#pragma unroll
  for (int o=32; o>0; o>>=1){
    den0 += __shfl_xor(den0, o);
    den1 += __shfl_xor(den1, o);
    den2 += __shfl_xor(den2, o);
    den3 += __shfl_xor(den3, o);
  }
  den0 += e0; den1 += e1; den2 += e2; den3 += e3;
  float* ab = &agg[(size_t)w*HD + c];
  ab[0*D] = o0 * (0.25f/den0);
  ab[1*D] = o1 * (0.25f/den1);
  ab[2*D] = o2 * (0.25f/den2);
  ab[3*D] = o3 * (0.25f/den3);
}

// ---------------- Fused GAT projection + MLP + heads ----------------
// Per 32-row block: h2 = relu(sum_h agg_h@W_h + gat_b) built in registers,
// written in-place into LDS S; then 2 MLP layers in place; then mu/lv heads.
// LDS = S(16.9 KB) + Ws(34.8 KB) = 51.7 KB -> 3 blocks/CU.
#define KLOOP(ACC)                                            \
  _Pragma("unroll 4")                                         \
  for (int k=0;k<128;k++){                                    \
    float4 wvv = *(const float4*)&Ws[k][tx<<2];               \
    float av0 = S[(ty<<1)+0][k];                              \
    float av1 = S[(ty<<1)+1][k];                              \
    ACC[0][0] = fmaf(av0, wvv.x, ACC[0][0]);                  \
    ACC[0][1] = fmaf(av0, wvv.y, ACC[0][1]);                  \
    ACC[0][2] = fmaf(av0, wvv.z, ACC[0][2]);                  \
    ACC[0][3] = fmaf(av0, wvv.w, ACC[0][3]);                  \
    ACC[1][0] = fmaf(av1, wvv.x, ACC[1][0]);                  \
    ACC[1][1] = fmaf(av1, wvv.y, ACC[1][1]);                  \
    ACC[1][2] = fmaf(av1, wvv.z, ACC[1][2]);                  \
    ACC[1][3] = fmaf(av1, wvv.w, ACC[1][3]);                  \
  }

__global__ __launch_bounds__(256) void k_gat_mlp(const float* __restrict__ agg,
                                                 const float* __restrict__ gat_w,
                                                 const float* __restrict__ gat_b,
                                                 const float* __restrict__ w1,
                                                 const float* __restrict__ b1,
                                                 const float* __restrict__ w2,
                                                 const float* __restrict__ b2,
                                                 const float* __restrict__ wmu,
                                                 const float* __restrict__ bmu,
                                                 const float* __restrict__ wlv,
                                                 const float* __restrict__ blv,
                                                 float* __restrict__ out){
  __shared__ float S[32][132];
  __shared__ float Ws[128][68];
  const int tid  = threadIdx.x;
  const int row0 = blockIdx.x*32;
  const int tx = tid & 15, ty = tid >> 4;
  float accA[2][4] = {{0.f}};
  float accB[2][4] = {{0.f}};

  // ---- Phase A: h2 accumulation over 4 heads ----
  for (int h=0; h<NH; h++){
    __syncthreads();              // S re-stage vs previous K-loop reads
#pragma unroll
    for (int i=0;i<4;i++){        // stage agg_h tile (32 x 32 float4)
      int f  = tid + i*256;
      int r  = f >> 5;
      int k4 = (f & 31) << 2;
      int rr = row0 + r;
      float4 v = make_float4(0.f,0.f,0.f,0.f);
      if (rr < NN) v = *(const float4*)&agg[(size_t)rr*HD + h*D + k4];
      *(float4*)&S[r][k4] = v;
    }
    // cc = 0
    __syncthreads();
#pragma unroll
    for (int i=0;i<8;i++){
      int f  = tid + i*256;
      int k  = f >> 4;
      int c4 = (f & 15) << 2;
      *(float4*)&Ws[k][c4] = *(const float4*)&gat_w[k*HD + h*D + 0 + c4];
    }
    __syncthreads();
    KLOOP(accA)
    // cc = 1
    __syncthreads();
#pragma unroll
    for (int i=0;i<8;i++){
      int f  = tid + i*256;
      int k  = f >> 4;
      int c4 = (f & 15) << 2;
      *(float4*)&Ws[k][c4] = *(const float4*)&gat_w[k*HD + h*D + 64 + c4];
    }
    __syncthreads();
    KLOOP(accB)
  }
  __syncthreads();                // all reads of S done
#pragma unroll
  for (int i=0;i<2;i++)
#pragma unroll
    for (int j=0;j<4;j++){
      int c0 = (tx<<2) + j;
      S[(ty<<1)+i][c0]      = fmaxf(accA[i][j] + gat_b[c0],      0.f);
      S[(ty<<1)+i][c0 + 64] = fmaxf(accB[i][j] + gat_b[c0 + 64], 0.f);
    }

  // ---- Phase B: two MLP layers, in place ----
  for (int layer=0; layer<2; layer++){
    const float* W  = layer ? w2 : w1;
    const float* bb = layer ? b2 : b1;
#pragma unroll
    for (int i=0;i<2;i++)
#pragma unroll
      for (int j=0;j<4;j++){ accA[i][j] = 0.f; accB[i][j] = 0.f; }
    // cc = 0
    __syncthreads();              // S writes visible; Ws protect
#pragma unroll
    for (int i=0;i<8;i++){
      int f  = tid + i*256;
      int k  = f >> 4;
      int c4 = (f & 15) << 2;
      *(float4*)&Ws[k][c4] = *(const float4*)&W[k*D + 0 + c4];
    }
    __syncthreads();
    KLOOP(accA)
    // cc = 1
    __syncthreads();
#pragma unroll
    for (int i=0;i<8;i++){
      int f  = tid + i*256;
      int k  = f >> 4;
      int c4 = (f & 15) << 2;
      *(float4*)&Ws[k][c4] = *(const float4*)&W[k*D + 64 + c4];
    }
    __syncthreads();
    KLOOP(accB)
    __syncthreads();              // all reads done before in-place write
#pragma unroll
    for (int i=0;i<2;i++)
#pragma unroll
      for (int j=0;j<4;j++){
        int c0 = (tx<<2) + j;
        S[(ty<<1)+i][c0]      = fmaxf(accA[i][j] + bb[c0],      0.f);
        S[(ty<<1)+i][c0 + 64] = fmaxf(accB[i][j] + bb[c0 + 64], 0.f);
      }
  }

  // ---- Phase C: mu / lv heads (64 cols each) ----
  for (int hd=0; hd<2; hd++){
    const float* W  = hd ? wlv : wmu;
    const float* bb = hd ? blv : bmu;
    float* ob = out + (size_t)hd*NN*ZD;
#pragma unroll
    for (int i=0;i<2;i++)
#pragma unroll
      for (int j=0;j<4;j++) accA[i][j] = 0.f;
    __syncthreads();              // S writes visible; Ws protect
#pragma unroll
    for (int i=0;i<8;i++){
      int f  = tid + i*256;
      int k  = f >> 4;
      int c4 = (f & 15) << 2;
      *(float4*)&Ws[k][c4] = *(const float4*)&W[k*ZD + c4];
    }
    __syncthreads();
    KLOOP(accA)
#pragma unroll
    for (int i=0;i<2;i++){
      int r = row0 + (ty<<1) + i;
      if (r >= NN) continue;
      float4 v = make_float4(accA[i][0] + bb[(tx<<2)+0],
                             accA[i][1] + bb[(tx<<2)+1],
                             accA[i][2] + bb[(tx<<2)+2],
                             accA[i][3] + bb[(tx<<2)+3]);
      *(float4*)&ob[r*ZD + (tx<<2)] = v;
    }
  }
}

extern "C" void kernel_launch(void* const* d_in, const int* in_sizes, int n_in,
                              void* d_out, int out_size, void* d_ws, size_t ws_size,
                              hipStream_t stream){
  const float* x     = (const float*)d_in[0];
  const int*   ei    = (const int*)d_in[1];
  const float* gcn_w = (const float*)d_in[2];
  const float* gcn_b = (const float*)d_in[3];
  const float* gat_w = (const float*)d_in[4];
  const float* att_s = (const float*)d_in[5];
  const float* att_d = (const float*)d_in[6];
  const float* gat_b = (const float*)d_in[7];
  const float* w1    = (const float*)d_in[8];
  const float* b1    = (const float*)d_in[9];
  const float* w2    = (const float*)d_in[10];
  const float* b2    = (const float*)d_in[11];
  const float* mu_w  = (const float*)d_in[12];
  const float* mu_b  = (const float*)d_in[13];
  const float* lv_w  = (const float*)d_in[14];
  const float* lv_b  = (const float*)d_in[15];
  const int E = in_sizes[1] / 2;
  const int* src = ei;
  const int* dst = ei + E;

  float* ws    = (float*)d_ws;
  float* xw    = ws;                 // N*128 (GCN projection)
  float* h1    = xw + NN*D;          // N*128 (GCN output)
  float* agg   = h1 + NN*D;          // N*512 (per-head h1-space aggregates)
  float* dinv  = agg + (size_t)NN*HD;// N
  float* w_as  = dinv + NN;          // 512
  float* w_ad  = w_as + HD;          // 512
  float* a_src = w_ad + HD;          // N*4
  float* a_dst = a_src + NN*NH;      // N*4 (contiguous with a_src)
  int*   ioff  = (int*)(a_dst + NN*NH);  // N+1
  int*   icur  = ioff + NN + 1;          // N
  int*   csr   = icur + NN;              // E

  const int gE = (E + 255)/256;
  const int gM = (NN + 31)/32;

  // front: GCN-proj GEMM + watt + icur zero (merged, independent work)
  k_mega<<<358, 256, 0, stream>>>(x, gcn_w, xw, gat_w, att_s, att_d,
                                  w_as, w_ad, icur);
  // CSR build
  k_hist<<<gE, 256, 0, stream>>>(dst, icur, E);
  k_scan<<<1, 1024, 0, stream>>>(icur, ioff, dinv);
  k_fill<<<gE, 256, 0, stream>>>(src, dst, icur, csr, E, a_src);

  // GCN gather (+ fused attention logits)
  k_gcn_agg<<<(NN/16)*8, 256, 0, stream>>>(xw, dinv, ioff, csr, gcn_b,
                                           w_as, w_ad, h1, a_src, a_dst);
  // GAT gather in h1-space
  k_gat_agg2<<<(NN/16)*8, 256, 0, stream>>>(h1, a_src, a_dst, ioff, csr, agg);
  // GAT projection + MLP + heads, fused
  k_gat_mlp<<<gM, 256, 0, stream>>>(agg, gat_w, gat_b, w1, b1, w2, b2,
                                    mu_w, mu_b, lv_w, lv_b, (float*)d_out);
}